// Round 2
// 996.596 us; speedup vs baseline: 1.0870x; 1.0870x over previous
//
#include <hip/hip_runtime.h>

// ---------------------------------------------------------------------------
// DTFDynamicLayer: router top-k gather -> Qwen2 block (bf16 MFMA GEMMs,
// MFMA flash attention) -> gated scatter.  B=2,T=2048,D=2048,H=16,HD=128,
// I=5632, K=1024, S=2048.  All fixed at compile time.
// ---------------------------------------------------------------------------

typedef unsigned short u16;
typedef unsigned int u32;
typedef short bf16x8 __attribute__((ext_vector_type(8)));
typedef float f32x4 __attribute__((ext_vector_type(4)));

#define T_LEN 2048
#define D_DIM 2048
#define B_DIM 2
#define H_NUM 16
#define HD_DIM 128
#define I_DIM 5632
#define K_CAP 1024
#define S_TOT 2048
#define QKV_N 6144
#define GU_N 11264

__device__ __forceinline__ u16 f2bf(float f) {
  union { float f; u32 u; } a; a.f = f;
  u32 r = a.u + 0x7fffu + ((a.u >> 16) & 1u);
  return (u16)(r >> 16);
}
__device__ __forceinline__ float bf2f(u16 x) {
  return __uint_as_float((u32)x << 16);
}

__device__ __forceinline__ void gld_lds16(const void* g, void* l) {
  void* gg = const_cast<void*>(g);
  __builtin_amdgcn_global_load_lds(
      (__attribute__((address_space(1))) u32*)gg,
      (__attribute__((address_space(3))) u32*)l, 16, 0, 0);
}

// ---------------- router: scores[b,t] = bcu*||o-p|| + bce*(||p-pr||+off) ----
__global__ __launch_bounds__(256)
void router_kernel(const float* __restrict__ orig, const float* __restrict__ post,
                   const float* __restrict__ prior, const float* __restrict__ bce,
                   const float* __restrict__ bcu, const float* __restrict__ coff,
                   float* __restrict__ scores) {
  const int row = blockIdx.x;
  const size_t base = (size_t)row * D_DIM;
  float s1 = 0.f, s2 = 0.f;
  for (int d = threadIdx.x * 4; d < D_DIM; d += 1024) {
    float4 o = *(const float4*)(orig + base + d);
    float4 p = *(const float4*)(post + base + d);
    float4 r = *(const float4*)(prior + base + d);
    float a;
    a = o.x - p.x; s1 += a * a;  a = o.y - p.y; s1 += a * a;
    a = o.z - p.z; s1 += a * a;  a = o.w - p.w; s1 += a * a;
    a = p.x - r.x; s2 += a * a;  a = p.y - r.y; s2 += a * a;
    a = p.z - r.z; s2 += a * a;  a = p.w - r.w; s2 += a * a;
  }
#pragma unroll
  for (int k = 32; k; k >>= 1) { s1 += __shfl_down(s1, k); s2 += __shfl_down(s2, k); }
  __shared__ float r1[4], r2[4];
  const int wv = threadIdx.x >> 6;
  if ((threadIdx.x & 63) == 0) { r1[wv] = s1; r2[wv] = s2; }
  __syncthreads();
  if (threadIdx.x == 0) {
    float cu = sqrtf(r1[0] + r1[1] + r1[2] + r1[3]);
    float ce = sqrtf(r2[0] + r2[1] + r2[2] + r2[3]);
    scores[row] = bcu[0] * cu + bce[0] * (ce + coff[0]);
  }
}

// ---------------- rank: stable top-k rank (matches lax.top_k tie-break) -----
__global__ __launch_bounds__(256)
void rank_kernel(const float* __restrict__ scores, int* __restrict__ rnk) {
  const int b = blockIdx.y;
  const int t = blockIdx.x * 256 + threadIdx.x;
  __shared__ float s[T_LEN];
  for (int u = threadIdx.x; u < T_LEN; u += 256) s[u] = scores[b * T_LEN + u];
  __syncthreads();
  const float st = s[t];
  int r = 0;
  for (int u = 0; u < T_LEN; ++u) {
    float su = s[u];
    r += ((su > st) || (su == st && u < t)) ? 1 : 0;
  }
  rnk[b * T_LEN + t] = r;
}

// ---------------- compact: selected (rank<K) in temporal order --------------
__global__ __launch_bounds__(256)
void compact_kernel(const float* __restrict__ scores, const int* __restrict__ rnk,
                    int* __restrict__ tidx, float* __restrict__ gate) {
  const int b = blockIdx.x;
  const int base = b * T_LEN;
  __shared__ int csum[256];
  int f[8]; int loc = 0;
  const int t0 = threadIdx.x * 8;
#pragma unroll
  for (int i = 0; i < 8; ++i) { f[i] = (rnk[base + t0 + i] < K_CAP) ? 1 : 0; loc += f[i]; }
  csum[threadIdx.x] = loc;
  __syncthreads();
  if (threadIdx.x == 0) {
    int run = 0;
    for (int i = 0; i < 256; ++i) { int tmp = csum[i]; csum[i] = run; run += tmp; }
  }
  __syncthreads();
  int pos = csum[threadIdx.x];
#pragma unroll
  for (int i = 0; i < 8; ++i) {
    if (f[i]) {
      float sc = scores[base + t0 + i];
      tidx[b * K_CAP + pos] = t0 + i;
      gate[b * K_CAP + pos] = 1.f / (1.f + __expf(-sc));
      ++pos;
    }
  }
}

// ---------------- weight transpose + bf16 convert: Wt[n][k] = W[k][n] -------
__global__ __launch_bounds__(256)
void transpose_bf16_kernel(const float* __restrict__ W, u16* __restrict__ Wt,
                           int K, int N) {
  __shared__ float tile[32][33];
  const int bn = blockIdx.x * 32, bk = blockIdx.y * 32;
  const int tx = threadIdx.x & 31, ty = threadIdx.x >> 5;
#pragma unroll
  for (int i = 0; i < 32; i += 8)
    tile[ty + i][tx] = W[(size_t)(bk + ty + i) * N + bn + tx];
  __syncthreads();
#pragma unroll
  for (int i = 0; i < 32; i += 8)
    Wt[(size_t)(bn + ty + i) * K + bk + tx] = f2bf(tile[tx][ty + i]);
}

// ---------------- V pre-transpose: qkv[s][4096+c] -> VT[c][s] (bf16) --------
__global__ __launch_bounds__(256)
void vtrans_kernel(const u16* __restrict__ qkv, u16* __restrict__ VT) {
  __shared__ u16 tile[32][34];
  const int s0 = blockIdx.x * 32;
  const int c0 = blockIdx.y * 32;
  const int tx = threadIdx.x & 31, ty = threadIdx.x >> 5;
#pragma unroll
  for (int i = 0; i < 32; i += 8)
    tile[ty + i][tx] = qkv[(size_t)(s0 + ty + i) * QKV_N + 4096 + c0 + tx];
  __syncthreads();
#pragma unroll
  for (int i = 0; i < 32; i += 8)
    VT[(size_t)(c0 + ty + i) * S_TOT + s0 + tx] = tile[tx][ty + i];
}

// ---------------- rmsnorm (optional gather, optional f32 copy, bf16 out) ----
__global__ __launch_bounds__(256)
void rmsnorm_kernel(const float* __restrict__ X, const int* __restrict__ tidx,
                    const float* __restrict__ w, float* __restrict__ xcopy,
                    u16* __restrict__ Y) {
  const int s = blockIdx.x;
  const float* row;
  if (tidx) {
    const int b = s >> 10;
    const int t = tidx[s];
    row = X + ((size_t)b * T_LEN + t) * D_DIM;
  } else {
    row = X + (size_t)s * D_DIM;
  }
  const int d0 = threadIdx.x * 4;
  float4 v0 = *(const float4*)(row + d0);
  float4 v1 = *(const float4*)(row + d0 + 1024);
  float ss = v0.x*v0.x + v0.y*v0.y + v0.z*v0.z + v0.w*v0.w
           + v1.x*v1.x + v1.y*v1.y + v1.z*v1.z + v1.w*v1.w;
#pragma unroll
  for (int k = 32; k; k >>= 1) ss += __shfl_down(ss, k);
  __shared__ float red[4];
  if ((threadIdx.x & 63) == 0) red[threadIdx.x >> 6] = ss;
  __syncthreads();
  const float tot = red[0] + red[1] + red[2] + red[3];
  const float rms = rsqrtf(tot * (1.0f / D_DIM) + 1e-6f);
  if (xcopy) {
    *(float4*)(xcopy + (size_t)s * D_DIM + d0) = v0;
    *(float4*)(xcopy + (size_t)s * D_DIM + d0 + 1024) = v1;
  }
  const float4 w0 = *(const float4*)(w + d0);
  const float4 w1 = *(const float4*)(w + d0 + 1024);
  u16* yp = Y + (size_t)s * D_DIM;
  u32 a0 = (u32)f2bf(v0.x * rms * w0.x) | ((u32)f2bf(v0.y * rms * w0.y) << 16);
  u32 a1 = (u32)f2bf(v0.z * rms * w0.z) | ((u32)f2bf(v0.w * rms * w0.w) << 16);
  *(uint2*)(yp + d0) = make_uint2(a0, a1);
  u32 b0 = (u32)f2bf(v1.x * rms * w1.x) | ((u32)f2bf(v1.y * rms * w1.y) << 16);
  u32 b1 = (u32)f2bf(v1.z * rms * w1.z) | ((u32)f2bf(v1.w * rms * w1.w) << 16);
  *(uint2*)(yp + d0 + 1024) = make_uint2(b0, b1);
}

// ---------------- bf16 MFMA GEMM, m97 structure -----------------------------
// C = A[M,K](bf16) x Bt[N,K](bf16)^T (+bias[col]) (+resid[M,N])
// output: fp32 C  OR bf16 Cbf (exactly one non-null).
__global__ __launch_bounds__(256)
void gemm_bf16_kernel(const u16* __restrict__ A, const u16* __restrict__ Bt,
                      float* __restrict__ C, u16* __restrict__ Cbf,
                      const float* __restrict__ bias,
                      const float* __restrict__ resid, int N, int K) {
  __shared__ u16 As[128 * 32];
  __shared__ u16 Bs[128 * 32];
  const int tid = threadIdx.x;
  const int w = tid >> 6, l = tid & 63;
  const int row0 = blockIdx.y * 128, col0 = blockIdx.x * 128;
  const int wr = (w >> 1) * 64, wc = (w & 1) * 64;
  const int am = l & 15, ak = (l >> 4) * 8;
  const int srow = l >> 2, scol = (l & 3) * 8;

  f32x4 acc[4][4] = {};

  const u16* Abase = A + (size_t)(row0 + srow) * K + scol;
  const u16* Bbase = Bt + (size_t)(col0 + srow) * K + scol;
  const int R0 = (w * 2) * 16, R1 = (w * 2 + 1) * 16;

  for (int k0 = 0; k0 < K; k0 += 32) {
    gld_lds16(Abase + (size_t)R0 * K + k0, &As[R0 * 32]);
    gld_lds16(Abase + (size_t)R1 * K + k0, &As[R1 * 32]);
    gld_lds16(Bbase + (size_t)R0 * K + k0, &Bs[R0 * 32]);
    gld_lds16(Bbase + (size_t)R1 * K + k0, &Bs[R1 * 32]);
    __syncthreads();
    bf16x8 af[4], bfr[4];
#pragma unroll
    for (int i = 0; i < 4; ++i) af[i] = *(const bf16x8*)&As[(wr + i * 16 + am) * 32 + ak];
#pragma unroll
    for (int j = 0; j < 4; ++j) bfr[j] = *(const bf16x8*)&Bs[(wc + j * 16 + am) * 32 + ak];
#pragma unroll
    for (int i = 0; i < 4; ++i)
#pragma unroll
      for (int j = 0; j < 4; ++j)
        acc[i][j] = __builtin_amdgcn_mfma_f32_16x16x32_bf16(af[i], bfr[j], acc[i][j], 0, 0, 0);
    __syncthreads();
  }

  const int rb = wr + (l >> 4) * 4;
  const int cb = wc + (l & 15);
#pragma unroll
  for (int i = 0; i < 4; ++i) {
#pragma unroll
    for (int j = 0; j < 4; ++j) {
      const int colg = col0 + cb + j * 16;
      const float bv = bias ? bias[colg] : 0.0f;
#pragma unroll
      for (int r = 0; r < 4; ++r) {
        const int rowg = row0 + rb + i * 16 + r;
        const size_t idx = (size_t)rowg * N + colg;
        float v = acc[i][j][r] + bv;
        if (resid) v += resid[idx];
        if (Cbf) Cbf[idx] = f2bf(v);
        else C[idx] = v;
      }
    }
  }
}

// ---------------- RoPE in place on bf16 qkv buffer [S, 6144] ----------------
__global__ __launch_bounds__(256)
void rope_kernel(u16* __restrict__ qkv, const float* __restrict__ cosb,
                 const float* __restrict__ sinb, const int* __restrict__ tidx) {
  const int idx = blockIdx.x * 256 + threadIdx.x;  // < S*H*64
  const int d = idx & 63;
  const int h = (idx >> 6) & 15;
  const int s = idx >> 10;
  const int b = s >> 10;
  const int t = tidx[s];
  const size_t base = (size_t)s * QKV_N + h * 128 + d;
  const size_t cb = ((size_t)b * T_LEN + t) * HD_DIM + d;
  const float c1 = cosb[cb], sn1 = sinb[cb];
  const float c2 = cosb[cb + 64], sn2 = sinb[cb + 64];
  float x1v, x2v;
  x1v = bf2f(qkv[base]); x2v = bf2f(qkv[base + 64]);
  qkv[base] = f2bf(x1v * c1 - x2v * sn1);
  qkv[base + 64] = f2bf(x2v * c2 + x1v * sn2);
  x1v = bf2f(qkv[base + 2048]); x2v = bf2f(qkv[base + 2048 + 64]);
  qkv[base + 2048] = f2bf(x1v * c1 - x2v * sn1);
  qkv[base + 2048 + 64] = f2bf(x2v * c2 + x1v * sn2);
}

// ---------------- MFMA flash attention (8 waves, 2 kv-groups) ---------------
// grid (32, H); block 512 (8 waves).  h<8: qt=31-bx, h>=8: qt=bx  (so block
// ids i and i+256 -- which land on the same CU under round-robin dispatch --
// carry complementary work).  Waves 0-3 = group 0 (even kv tiles), waves
// 4-7 = group 1 (odd kv tiles); in-LDS (m,l,O) merge at the end.
// V comes pre-transposed (VT[h*128+d][s]); K/V staged with global_load_lds
// into XOR-swizzled LDS (linear dest, inverse-swizzled per-lane source).
// LDS = 64 KiB exactly: Ps aliases the first half of Ks (safe: an extra
// block barrier separates the last Ks read (QK^T) from the first Ps write).
__global__ __launch_bounds__(512, 4)
void attn_mfma_kernel(const u16* __restrict__ QKV, const u16* __restrict__ VT,
                      u16* __restrict__ Og) {
  const int h  = blockIdx.y;
  const int bx = blockIdx.x;
  const int qt = (h < 8) ? (31 - bx) : bx;
  const int q0 = qt * 64;
  const int tid = threadIdx.x;
  const int l  = tid & 63;
  const int w  = tid >> 6;       // 0..7
  const int g  = w >> 2;         // kv group
  const int wq = w & 3;          // q sub-block (16 rows)
  const int lm = l & 15, lk = l >> 4;

  __shared__ __align__(16) unsigned char smem[65536];
  u16* Ks = (u16*)(smem + g * 16384);           // [64 kv][128 d]  swizzled
  u16* Vt = (u16*)(smem + 32768 + g * 16384);   // [128 d][64 kv]  swizzled
  u16* Ps = (u16*)(smem + g * 16384);           // [64 q][64 kv]   aliases Ks

  const u16* Qg  = QKV + h * 128;
  const u16* Kg  = QKV + 2048 + h * 128;
  const u16* Vgt = VT + (size_t)h * 128 * S_TOT;

  // Q fragments: rows q0 + wq*16 + lm, k-chunks of 32 over d=128
  bf16x8 qf[4];
  {
    const u16* qrow = Qg + (size_t)(q0 + wq * 16 + lm) * QKV_N;
#pragma unroll
    for (int ks = 0; ks < 4; ++ks) qf[ks] = *(const bf16x8*)&qrow[ks * 32 + lk * 8];
  }

  // per-lane inverse-swizzled staging source offsets (u16 units in-plane).
  // chunk ci = (wq*4+p)*64 + l ; LDS gets linear base + lane*16.
  int ksrc[4], vsrc[4];
#pragma unroll
  for (int p = 0; p < 4; ++p) {
    const int ci = (wq * 4 + p) * 64 + l;
    const int kr = ci >> 4, kc = ci & 15;        // K: row=kv (0..63), 16 chunks/row
    ksrc[p] = kr * QKV_N + ((kc ^ (kr & 7)) * 8);
    const int vr = ci >> 3, vc = ci & 7;         // V^T: row=d (0..127), 8 chunks/row
    vsrc[p] = vr * S_TOT + ((vc ^ (vr & 7)) * 8);
  }

  f32x4 oacc[8];
#pragma unroll
  for (int n = 0; n < 8; ++n) oacc[n] = (f32x4){0.f, 0.f, 0.f, 0.f};
  float m_run[4] = {-1e30f, -1e30f, -1e30f, -1e30f};
  float l_run[4] = {0.f, 0.f, 0.f, 0.f};

  const int ntiles = (g == 0) ? (qt / 2 + 1) : ((qt + 1) / 2);  // my kv tiles
  const int nmax = qt / 2 + 1;                                   // uniform trip
  const float scale = 0.08838834764831845f;  // 1/sqrt(128)

  for (int it = 0; it < nmax; ++it) {
    const int kt = g + 2 * it;
    const int kv0 = kt * 64;
    const bool active = (it < ntiles);
    __syncthreads();                     // previous tile fully consumed
    if (active) {
#pragma unroll
      for (int p = 0; p < 4; ++p) {
        gld_lds16(Kg + (size_t)kv0 * QKV_N + ksrc[p], &Ks[(wq * 4 + p) * 512]);
        gld_lds16(Vgt + kv0 + vsrc[p],               &Vt[(wq * 4 + p) * 512]);
      }
    }
    __syncthreads();                     // staging visible

    f32x4 sacc[4];
    if (active) {
      // QK^T: S[16q x 64kv] per wave
#pragma unroll
      for (int j = 0; j < 4; ++j) sacc[j] = (f32x4){0.f, 0.f, 0.f, 0.f};
#pragma unroll
      for (int j = 0; j < 4; ++j) {
        const int row = j * 16 + lm;
#pragma unroll
        for (int ks = 0; ks < 4; ++ks) {
          const int c = ks * 4 + lk;
          const bf16x8 kf = *(const bf16x8*)&(
              (const unsigned char*)Ks)[row * 256 + ((c ^ (row & 7)) << 4)];
          sacc[j] = __builtin_amdgcn_mfma_f32_16x16x32_bf16(qf[ks], kf, sacc[j], 0, 0, 0);
        }
      }
    }
    __syncthreads();                     // all Ks reads done; Ps may overwrite

    if (active) {
      // mask + online softmax (in registers, per 16-lane group)
      float mx[4] = {-1e30f, -1e30f, -1e30f, -1e30f};
#pragma unroll
      for (int j = 0; j < 4; ++j) {
        const int colg = kv0 + j * 16 + lm;
#pragma unroll
        for (int r = 0; r < 4; ++r) {
          const int rowg = q0 + wq * 16 + lk * 4 + r;
          float s = sacc[j][r] * scale;
          s = (colg > rowg) ? -1e30f : s;
          sacc[j][r] = s;
          mx[r] = fmaxf(mx[r], s);
        }
      }
#pragma unroll
      for (int r = 0; r < 4; ++r)
#pragma unroll
        for (int dlt = 1; dlt < 16; dlt <<= 1)
          mx[r] = fmaxf(mx[r], __shfl_xor(mx[r], dlt));
      float alpha[4];
#pragma unroll
      for (int r = 0; r < 4; ++r) {
        const float mnew = fmaxf(m_run[r], mx[r]);
        const float al = __expf(m_run[r] - mnew);
        float sum = 0.f;
#pragma unroll
        for (int j = 0; j < 4; ++j) {
          const float pe = __expf(sacc[j][r] - mnew);
          sacc[j][r] = pe;
          sum += pe;
        }
#pragma unroll
        for (int dlt = 1; dlt < 16; dlt <<= 1) sum += __shfl_xor(sum, dlt);
        l_run[r] = l_run[r] * al + sum;
        m_run[r] = mnew;
        alpha[r] = al;
      }
#pragma unroll
      for (int n = 0; n < 8; ++n)
#pragma unroll
        for (int r = 0; r < 4; ++r) oacc[n][r] *= alpha[r];

      // P (C-layout) -> Ps (A-layout, swizzled); wave-local rows
#pragma unroll
      for (int j = 0; j < 4; ++j)
#pragma unroll
        for (int r = 0; r < 4; ++r) {
          const int row = wq * 16 + lk * 4 + r;
          *(u16*)&((unsigned char*)Ps)[row * 128 +
              (((j * 16 + lm) * 2) ^ ((row & 7) << 4))] = f2bf(sacc[j][r]);
        }

      // PV: O[16q x 128d] += P[16 x 64] * V[64 x 128]
#pragma unroll
      for (int ks2 = 0; ks2 < 2; ++ks2) {
        const int prow = wq * 16 + lm;
        const bf16x8 pf = *(const bf16x8*)&(
            (const unsigned char*)Ps)[prow * 128 +
                ((ks2 * 64 + lk * 16) ^ ((prow & 7) << 4))];
#pragma unroll
        for (int n = 0; n < 8; ++n) {
          const int vrow = n * 16 + lm;
          const int vc = ks2 * 4 + lk;
          const bf16x8 vf = *(const bf16x8*)&(
              (const unsigned char*)Vt)[vrow * 128 + ((vc ^ (vrow & 7)) << 4)];
          oacc[n] = __builtin_amdgcn_mfma_f32_16x16x32_bf16(pf, vf, oacc[n], 0, 0, 0);
        }
      }
    }
  }

  // ---- merge the two kv-groups via LDS (reuses staging space) ----
  __syncthreads();
  float* Obuf = (float*)smem;              // [64][132] f32 (padded)
  float* Mbuf = (float*)(smem + 33792);    // [64]
  float* Lbuf = (float*)(smem + 34048);    // [64]
  if (g == 1) {
#pragma unroll
    for (int r = 0; r < 4; ++r) {
      const int row = wq * 16 + lk * 4 + r;
      if (lm == 0) { Mbuf[row] = m_run[r]; Lbuf[row] = l_run[r]; }
#pragma unroll
      for (int n = 0; n < 8; ++n) Obuf[row * 132 + n * 16 + lm] = oacc[n][r];
    }
  }
  __syncthreads();
  if (g == 0) {
    float a0[4], a1[4], linv[4];
#pragma unroll
    for (int r = 0; r < 4; ++r) {
      const int row = wq * 16 + lk * 4 + r;
      const float m1 = Mbuf[row], l1 = Lbuf[row];
      const float M = fmaxf(m_run[r], m1);
      a0[r] = __expf(m_run[r] - M);
      a1[r] = __expf(m1 - M);
      linv[r] = 1.f / (a0[r] * l_run[r] + a1[r] * l1);
    }
#pragma unroll
    for (int n = 0; n < 8; ++n)
#pragma unroll
      for (int r = 0; r < 4; ++r) {
        const int row = wq * 16 + lk * 4 + r;
        const float o = (oacc[n][r] * a0[r] +
                         Obuf[row * 132 + n * 16 + lm] * a1[r]) * linv[r];
        Og[(size_t)(q0 + row) * 2048 + h * 128 + n * 16 + lm] = f2bf(o);
      }
  }
}

// ---------------- silu(gate)*up on fused bf16 gu buffer ---------------------
__global__ __launch_bounds__(256)
void silu_mul_kernel(const u16* __restrict__ gu, u16* __restrict__ out) {
  const size_t i = (size_t)blockIdx.x * 256 + threadIdx.x;  // 4-elem units
  const int s = (int)(i / 1408);
  const int c = (int)(i - (size_t)s * 1408);
  const uint2 g4 = *(const uint2*)&gu[(size_t)s * GU_N + c * 4];
  const uint2 u4 = *(const uint2*)&gu[(size_t)s * GU_N + I_DIM + c * 4];
  float g[4], u[4];
  g[0] = __uint_as_float(g4.x << 16); g[1] = __uint_as_float(g4.x & 0xffff0000u);
  g[2] = __uint_as_float(g4.y << 16); g[3] = __uint_as_float(g4.y & 0xffff0000u);
  u[0] = __uint_as_float(u4.x << 16); u[1] = __uint_as_float(u4.x & 0xffff0000u);
  u[2] = __uint_as_float(u4.y << 16); u[3] = __uint_as_float(u4.y & 0xffff0000u);
  u16 r[4];
#pragma unroll
  for (int j = 0; j < 4; ++j) r[j] = f2bf(g[j] * u[j] / (1.f + __expf(-g[j])));
  u32 a0 = (u32)r[0] | ((u32)r[1] << 16);
  u32 a1 = (u32)r[2] | ((u32)r[3] << 16);
  *(uint2*)&out[(size_t)s * I_DIM + c * 4] = make_uint2(a0, a1);
}

// ---------------- gated scatter back ----------------------------------------
__global__ __launch_bounds__(256)
void scatter_kernel(const float* __restrict__ hs, const float* __restrict__ x2,
                    const int* __restrict__ tidx, const float* __restrict__ gate,
                    float* __restrict__ out) {
  const int s = blockIdx.x;
  const int b = s >> 10;
  const int t = tidx[s];
  const float gg = gate[s];
  const size_t src = (size_t)s * D_DIM;
  const size_t dst = ((size_t)b * T_LEN + t) * D_DIM;
  for (int d = threadIdx.x * 4; d < D_DIM; d += 1024) {
    float4 hv = *(const float4*)(hs + dst + d);
    float4 pv = *(const float4*)(x2 + src + d);
    float4 r;
    r.x = hv.x + (pv.x - hv.x) * gg;
    r.y = hv.y + (pv.y - hv.y) * gg;
    r.z = hv.z + (pv.z - hv.z) * gg;
    r.w = hv.w + (pv.w - hv.w) * gg;
    *(float4*)(out + dst + d) = r;
  }
}

// ---------------------------------------------------------------------------
extern "C" void kernel_launch(void* const* d_in, const int* in_sizes, int n_in,
                              void* d_out, int out_size, void* d_ws, size_t ws_size,
                              hipStream_t stream) {
  (void)in_sizes; (void)n_in; (void)out_size; (void)ws_size;
  const float* hs    = (const float*)d_in[0];
  const float* orig  = (const float*)d_in[1];
  const float* post  = (const float*)d_in[2];
  const float* prior = (const float*)d_in[3];
  const float* cosb  = (const float*)d_in[4];
  const float* sinb  = (const float*)d_in[5];
  const float* q_w = (const float*)d_in[7];
  const float* q_b = (const float*)d_in[8];
  const float* k_w = (const float*)d_in[9];
  const float* k_b = (const float*)d_in[10];
  const float* v_w = (const float*)d_in[11];
  const float* v_b = (const float*)d_in[12];
  const float* o_w = (const float*)d_in[13];
  const float* ln1 = (const float*)d_in[14];
  const float* ln2 = (const float*)d_in[15];
  const float* gate_w = (const float*)d_in[16];
  const float* up_w   = (const float*)d_in[17];
  const float* down_w = (const float*)d_in[18];
  const float* beta_ce = (const float*)d_in[19];
  const float* beta_cu = (const float*)d_in[20];
  const float* ce_off  = (const float*)d_in[21];
  float* out = (float*)d_out;

  char* wsp = (char*)d_ws;
  size_t off = 0;
  auto alloc = [&](size_t n) -> char* {
    char* r = wsp + off; off += (n + 255) & ~(size_t)255; return r;
  };
  const size_t SD4 = (size_t)S_TOT * D_DIM * 4;   // 16 MB

  float* scores  = (float*)alloc((size_t)B_DIM * T_LEN * 4);
  int*   rnk     = (int*)  alloc((size_t)B_DIM * T_LEN * 4);
  int*   tidx    = (int*)  alloc((size_t)S_TOT * 4);
  float* gatebuf = (float*)alloc((size_t)S_TOT * 4);
  float* qkvbias = (float*)alloc((size_t)QKV_N * 4);
  u16* qkvwt = (u16*)alloc((size_t)QKV_N * 2048 * 2);       // 25.2 MB
  u16* owt   = (u16*)alloc((size_t)2048 * 2048 * 2);        //  8.4 MB
  u16* guwt  = (u16*)alloc((size_t)GU_N * 2048 * 2);        // 46.1 MB
  u16* dwt   = (u16*)alloc((size_t)2048 * I_DIM * 2);       // 23.1 MB
  // region A: selh (rms1..O-proj) then h2 (rms2..gate/up)
  char* rA = alloc(SD4);
  float* selh = (float*)rA;
  u16*   h2   = (u16*)rA;
  // region B: h1 (rms1..QKV) then o_attn (attn..O-proj) then mlp_in (silu..down)
  char* rB = alloc((size_t)S_TOT * I_DIM * 2);              // 23.1 MB
  u16* h1     = (u16*)rB;
  u16* o_attn = (u16*)rB;
  u16* mlp_in = (u16*)rB;
  // region C: qkv_bf (QKV..attn) then gu_bf (gate/up..silu) then x2 (down..scatter)
  char* rC = alloc((size_t)S_TOT * GU_N * 2);               // 44 MB
  u16* qkv_bf = (u16*)rC;
  u16* gu_bf  = (u16*)rC;
  float* x2   = (float*)rC;
  float* x1 = (float*)alloc(SD4);
  // vT (pre-transposed V, 8 MB) lives in x1 -- x1 is only written at step 7,
  // after attention has consumed vT.
  u16* vT = (u16*)x1;

  // 0) output starts as a copy of hidden_states; fused qkv bias
  hipMemcpyAsync(out, hs, (size_t)B_DIM * T_LEN * D_DIM * 4,
                 hipMemcpyDeviceToDevice, stream);
  hipMemcpyAsync(qkvbias, q_b, 2048 * 4, hipMemcpyDeviceToDevice, stream);
  hipMemcpyAsync(qkvbias + 2048, k_b, 2048 * 4, hipMemcpyDeviceToDevice, stream);
  hipMemcpyAsync(qkvbias + 4096, v_b, 2048 * 4, hipMemcpyDeviceToDevice, stream);

  // 1) router scores + top-k selection (temporal order)
  router_kernel<<<dim3(B_DIM * T_LEN), 256, 0, stream>>>(orig, post, prior,
                                                         beta_ce, beta_cu, ce_off, scores);
  rank_kernel<<<dim3(8, B_DIM), 256, 0, stream>>>(scores, rnk);
  compact_kernel<<<dim3(B_DIM), 256, 0, stream>>>(scores, rnk, tidx, gatebuf);

  // 2) weight conversions (transpose to [N][K] bf16); fused layouts
  transpose_bf16_kernel<<<dim3(64, 64), 256, 0, stream>>>(q_w, qkvwt, 2048, 2048);
  transpose_bf16_kernel<<<dim3(64, 64), 256, 0, stream>>>(k_w, qkvwt + (size_t)2048 * 2048, 2048, 2048);
  transpose_bf16_kernel<<<dim3(64, 64), 256, 0, stream>>>(v_w, qkvwt + (size_t)4096 * 2048, 2048, 2048);
  transpose_bf16_kernel<<<dim3(64, 64), 256, 0, stream>>>(o_w, owt, 2048, 2048);
  transpose_bf16_kernel<<<dim3(176, 64), 256, 0, stream>>>(gate_w, guwt, 2048, I_DIM);
  transpose_bf16_kernel<<<dim3(176, 64), 256, 0, stream>>>(up_w, guwt + (size_t)I_DIM * 2048, 2048, I_DIM);
  transpose_bf16_kernel<<<dim3(64, 176), 256, 0, stream>>>(down_w, dwt, I_DIM, 2048);

  // 3) gather + rmsnorm1 -> selh (f32), h1 (bf16)
  rmsnorm_kernel<<<dim3(S_TOT), 256, 0, stream>>>(hs, tidx, ln1, selh, h1);

  // 4) fused QKV GEMM -> qkv_bf (bf16, [S][6144])
  gemm_bf16_kernel<<<dim3(48, 16), 256, 0, stream>>>(h1, qkvwt, nullptr, qkv_bf,
                                                     qkvbias, nullptr, QKV_N, 2048);
  // 5) RoPE in place (q & k halves)
  rope_kernel<<<dim3((S_TOT * H_NUM * 64) / 256), 256, 0, stream>>>(qkv_bf, cosb, sinb, tidx);

  // 5b) pre-transpose V -> vT[h*128+d][s]
  vtrans_kernel<<<dim3(64, 64), 256, 0, stream>>>(qkv_bf, vT);

  // 6) MFMA flash attention -> o_attn (bf16)
  attn_mfma_kernel<<<dim3(32, H_NUM), 512, 0, stream>>>(qkv_bf, vT, o_attn);

  // 7) O-proj + residual -> x1 (f32)
  gemm_bf16_kernel<<<dim3(16, 16), 256, 0, stream>>>(o_attn, owt, x1, nullptr,
                                                     nullptr, selh, 2048, 2048);

  // 8) rmsnorm2 -> h2 (bf16)
  rmsnorm_kernel<<<dim3(S_TOT), 256, 0, stream>>>(x1, nullptr, ln2, nullptr, h2);

  // 9) fused gate/up GEMM -> gu_bf (bf16, [S][11264])
  gemm_bf16_kernel<<<dim3(88, 16), 256, 0, stream>>>(h2, guwt, nullptr, gu_bf,
                                                     nullptr, nullptr, GU_N, 2048);

  // 10) silu * up -> mlp_in (bf16)
  silu_mul_kernel<<<dim3((S_TOT * (I_DIM / 4)) / 256), 256, 0, stream>>>(gu_bf, mlp_in);

  // 11) down GEMM + residual -> x2 (f32)
  gemm_bf16_kernel<<<dim3(16, 16), 256, 0, stream>>>(mlp_in, dwt, x2, nullptr,
                                                     nullptr, x1, 2048, I_DIM);

  // 12) gated scatter into out
  scatter_kernel<<<dim3(S_TOT), 256, 0, stream>>>(hs, x2, tidx, gatebuf, out);
}

// Round 3
// 923.107 us; speedup vs baseline: 1.1736x; 1.0796x over previous
//
#include <hip/hip_runtime.h>

// ---------------------------------------------------------------------------
// DTFDynamicLayer: router top-k gather -> Qwen2 block (bf16 MFMA GEMMs,
// MFMA flash attention) -> gated scatter.  B=2,T=2048,D=2048,H=16,HD=128,
// I=5632, K=1024, S=2048.  All fixed at compile time.
// ---------------------------------------------------------------------------

typedef unsigned short u16;
typedef unsigned int u32;
typedef short bf16x8 __attribute__((ext_vector_type(8)));
typedef float f32x4 __attribute__((ext_vector_type(4)));

#define T_LEN 2048
#define D_DIM 2048
#define B_DIM 2
#define H_NUM 16
#define HD_DIM 128
#define I_DIM 5632
#define K_CAP 1024
#define S_TOT 2048
#define QKV_N 6144
#define GU_N 11264

__device__ __forceinline__ u16 f2bf(float f) {
  union { float f; u32 u; } a; a.f = f;
  u32 r = a.u + 0x7fffu + ((a.u >> 16) & 1u);
  return (u16)(r >> 16);
}
__device__ __forceinline__ float bf2f(u16 x) {
  return __uint_as_float((u32)x << 16);
}

__device__ __forceinline__ void gld_lds16(const void* g, void* l) {
  void* gg = const_cast<void*>(g);
  __builtin_amdgcn_global_load_lds(
      (__attribute__((address_space(1))) u32*)gg,
      (__attribute__((address_space(3))) u32*)l, 16, 0, 0);
}

// ---------------- router: scores[b,t] = bcu*||o-p|| + bce*(||p-pr||+off) ----
__global__ __launch_bounds__(256)
void router_kernel(const float* __restrict__ orig, const float* __restrict__ post,
                   const float* __restrict__ prior, const float* __restrict__ bce,
                   const float* __restrict__ bcu, const float* __restrict__ coff,
                   float* __restrict__ scores) {
  const int row = blockIdx.x;
  const size_t base = (size_t)row * D_DIM;
  float s1 = 0.f, s2 = 0.f;
  for (int d = threadIdx.x * 4; d < D_DIM; d += 1024) {
    float4 o = *(const float4*)(orig + base + d);
    float4 p = *(const float4*)(post + base + d);
    float4 r = *(const float4*)(prior + base + d);
    float a;
    a = o.x - p.x; s1 += a * a;  a = o.y - p.y; s1 += a * a;
    a = o.z - p.z; s1 += a * a;  a = o.w - p.w; s1 += a * a;
    a = p.x - r.x; s2 += a * a;  a = p.y - r.y; s2 += a * a;
    a = p.z - r.z; s2 += a * a;  a = p.w - r.w; s2 += a * a;
  }
#pragma unroll
  for (int k = 32; k; k >>= 1) { s1 += __shfl_down(s1, k); s2 += __shfl_down(s2, k); }
  __shared__ float r1[4], r2[4];
  const int wv = threadIdx.x >> 6;
  if ((threadIdx.x & 63) == 0) { r1[wv] = s1; r2[wv] = s2; }
  __syncthreads();
  if (threadIdx.x == 0) {
    float cu = sqrtf(r1[0] + r1[1] + r1[2] + r1[3]);
    float ce = sqrtf(r2[0] + r2[1] + r2[2] + r2[3]);
    scores[row] = bcu[0] * cu + bce[0] * (ce + coff[0]);
  }
}

// ---------------- rank: stable top-k rank (matches lax.top_k tie-break) -----
__global__ __launch_bounds__(256)
void rank_kernel(const float* __restrict__ scores, int* __restrict__ rnk) {
  const int b = blockIdx.y;
  const int t = blockIdx.x * 256 + threadIdx.x;
  __shared__ float s[T_LEN];
  for (int u = threadIdx.x; u < T_LEN; u += 256) s[u] = scores[b * T_LEN + u];
  __syncthreads();
  const float st = s[t];
  int r = 0;
  for (int u = 0; u < T_LEN; ++u) {
    float su = s[u];
    r += ((su > st) || (su == st && u < t)) ? 1 : 0;
  }
  rnk[b * T_LEN + t] = r;
}

// ---------------- compact: selected (rank<K) in temporal order --------------
__global__ __launch_bounds__(256)
void compact_kernel(const float* __restrict__ scores, const int* __restrict__ rnk,
                    int* __restrict__ tidx, float* __restrict__ gate) {
  const int b = blockIdx.x;
  const int base = b * T_LEN;
  __shared__ int csum[256];
  int f[8]; int loc = 0;
  const int t0 = threadIdx.x * 8;
#pragma unroll
  for (int i = 0; i < 8; ++i) { f[i] = (rnk[base + t0 + i] < K_CAP) ? 1 : 0; loc += f[i]; }
  csum[threadIdx.x] = loc;
  __syncthreads();
  if (threadIdx.x == 0) {
    int run = 0;
    for (int i = 0; i < 256; ++i) { int tmp = csum[i]; csum[i] = run; run += tmp; }
  }
  __syncthreads();
  int pos = csum[threadIdx.x];
#pragma unroll
  for (int i = 0; i < 8; ++i) {
    if (f[i]) {
      float sc = scores[base + t0 + i];
      tidx[b * K_CAP + pos] = t0 + i;
      gate[b * K_CAP + pos] = 1.f / (1.f + __expf(-sc));
      ++pos;
    }
  }
}

// ---------------- weight transpose + bf16 convert: Wt[n][k] = W[k][n] -------
__global__ __launch_bounds__(256)
void transpose_bf16_kernel(const float* __restrict__ W, u16* __restrict__ Wt,
                           int K, int N) {
  __shared__ float tile[32][33];
  const int bn = blockIdx.x * 32, bk = blockIdx.y * 32;
  const int tx = threadIdx.x & 31, ty = threadIdx.x >> 5;
#pragma unroll
  for (int i = 0; i < 32; i += 8)
    tile[ty + i][tx] = W[(size_t)(bk + ty + i) * N + bn + tx];
  __syncthreads();
#pragma unroll
  for (int i = 0; i < 32; i += 8)
    Wt[(size_t)(bn + ty + i) * K + bk + tx] = f2bf(tile[tx][ty + i]);
}

// ---------------- V pre-transpose: qkv[s][4096+c] -> VT[c][s] (bf16) --------
__global__ __launch_bounds__(256)
void vtrans_kernel(const u16* __restrict__ qkv, u16* __restrict__ VT) {
  __shared__ u16 tile[32][34];
  const int s0 = blockIdx.x * 32;
  const int c0 = blockIdx.y * 32;
  const int tx = threadIdx.x & 31, ty = threadIdx.x >> 5;
#pragma unroll
  for (int i = 0; i < 32; i += 8)
    tile[ty + i][tx] = qkv[(size_t)(s0 + ty + i) * QKV_N + 4096 + c0 + tx];
  __syncthreads();
#pragma unroll
  for (int i = 0; i < 32; i += 8)
    VT[(size_t)(c0 + ty + i) * S_TOT + s0 + tx] = tile[tx][ty + i];
}

// ---------------- rmsnorm (optional gather, optional f32 copy, bf16 out) ----
__global__ __launch_bounds__(256)
void rmsnorm_kernel(const float* __restrict__ X, const int* __restrict__ tidx,
                    const float* __restrict__ w, float* __restrict__ xcopy,
                    u16* __restrict__ Y) {
  const int s = blockIdx.x;
  const float* row;
  if (tidx) {
    const int b = s >> 10;
    const int t = tidx[s];
    row = X + ((size_t)b * T_LEN + t) * D_DIM;
  } else {
    row = X + (size_t)s * D_DIM;
  }
  const int d0 = threadIdx.x * 4;
  float4 v0 = *(const float4*)(row + d0);
  float4 v1 = *(const float4*)(row + d0 + 1024);
  float ss = v0.x*v0.x + v0.y*v0.y + v0.z*v0.z + v0.w*v0.w
           + v1.x*v1.x + v1.y*v1.y + v1.z*v1.z + v1.w*v1.w;
#pragma unroll
  for (int k = 32; k; k >>= 1) ss += __shfl_down(ss, k);
  __shared__ float red[4];
  if ((threadIdx.x & 63) == 0) red[threadIdx.x >> 6] = ss;
  __syncthreads();
  const float tot = red[0] + red[1] + red[2] + red[3];
  const float rms = rsqrtf(tot * (1.0f / D_DIM) + 1e-6f);
  if (xcopy) {
    *(float4*)(xcopy + (size_t)s * D_DIM + d0) = v0;
    *(float4*)(xcopy + (size_t)s * D_DIM + d0 + 1024) = v1;
  }
  const float4 w0 = *(const float4*)(w + d0);
  const float4 w1 = *(const float4*)(w + d0 + 1024);
  u16* yp = Y + (size_t)s * D_DIM;
  u32 a0 = (u32)f2bf(v0.x * rms * w0.x) | ((u32)f2bf(v0.y * rms * w0.y) << 16);
  u32 a1 = (u32)f2bf(v0.z * rms * w0.z) | ((u32)f2bf(v0.w * rms * w0.w) << 16);
  *(uint2*)(yp + d0) = make_uint2(a0, a1);
  u32 b0 = (u32)f2bf(v1.x * rms * w1.x) | ((u32)f2bf(v1.y * rms * w1.y) << 16);
  u32 b1 = (u32)f2bf(v1.z * rms * w1.z) | ((u32)f2bf(v1.w * rms * w1.w) << 16);
  *(uint2*)(yp + d0 + 1024) = make_uint2(b0, b1);
}

// ---------------- bf16 MFMA GEMM, m97 structure -----------------------------
// C = A[M,K](bf16) x Bt[N,K](bf16)^T (+bias[col]) (+resid[M,N])
// output: fp32 C  OR bf16 Cbf (exactly one non-null).
__global__ __launch_bounds__(256)
void gemm_bf16_kernel(const u16* __restrict__ A, const u16* __restrict__ Bt,
                      float* __restrict__ C, u16* __restrict__ Cbf,
                      const float* __restrict__ bias,
                      const float* __restrict__ resid, int N, int K) {
  __shared__ u16 As[128 * 32];
  __shared__ u16 Bs[128 * 32];
  const int tid = threadIdx.x;
  const int w = tid >> 6, l = tid & 63;
  const int row0 = blockIdx.y * 128, col0 = blockIdx.x * 128;
  const int wr = (w >> 1) * 64, wc = (w & 1) * 64;
  const int am = l & 15, ak = (l >> 4) * 8;
  const int srow = l >> 2, scol = (l & 3) * 8;

  f32x4 acc[4][4] = {};

  const u16* Abase = A + (size_t)(row0 + srow) * K + scol;
  const u16* Bbase = Bt + (size_t)(col0 + srow) * K + scol;
  const int R0 = (w * 2) * 16, R1 = (w * 2 + 1) * 16;

  for (int k0 = 0; k0 < K; k0 += 32) {
    gld_lds16(Abase + (size_t)R0 * K + k0, &As[R0 * 32]);
    gld_lds16(Abase + (size_t)R1 * K + k0, &As[R1 * 32]);
    gld_lds16(Bbase + (size_t)R0 * K + k0, &Bs[R0 * 32]);
    gld_lds16(Bbase + (size_t)R1 * K + k0, &Bs[R1 * 32]);
    __syncthreads();
    bf16x8 af[4], bfr[4];
#pragma unroll
    for (int i = 0; i < 4; ++i) af[i] = *(const bf16x8*)&As[(wr + i * 16 + am) * 32 + ak];
#pragma unroll
    for (int j = 0; j < 4; ++j) bfr[j] = *(const bf16x8*)&Bs[(wc + j * 16 + am) * 32 + ak];
#pragma unroll
    for (int i = 0; i < 4; ++i)
#pragma unroll
      for (int j = 0; j < 4; ++j)
        acc[i][j] = __builtin_amdgcn_mfma_f32_16x16x32_bf16(af[i], bfr[j], acc[i][j], 0, 0, 0);
    __syncthreads();
  }

  const int rb = wr + (l >> 4) * 4;
  const int cb = wc + (l & 15);
#pragma unroll
  for (int i = 0; i < 4; ++i) {
#pragma unroll
    for (int j = 0; j < 4; ++j) {
      const int colg = col0 + cb + j * 16;
      const float bv = bias ? bias[colg] : 0.0f;
#pragma unroll
      for (int r = 0; r < 4; ++r) {
        const int rowg = row0 + rb + i * 16 + r;
        const size_t idx = (size_t)rowg * N + colg;
        float v = acc[i][j][r] + bv;
        if (resid) v += resid[idx];
        if (Cbf) Cbf[idx] = f2bf(v);
        else C[idx] = v;
      }
    }
  }
}

// ---------------- split-K bf16 MFMA GEMM (f32 partials) ---------------------
// P[z][row][col] = A[M,K] x Bt[N,K]^T over k in [z*kLen, (z+1)*kLen).
// M = S_TOT fixed; plane stride = S_TOT*N.  Used for the two grid-starved
// GEMMs (O-proj, down-proj) whose natural grid is only 256 blocks (1/CU):
// split-K=2 doubles resident blocks so barrier drains overlap across blocks.
__global__ __launch_bounds__(256)
void gemm_bf16_splitk_kernel(const u16* __restrict__ A, const u16* __restrict__ Bt,
                             float* __restrict__ P, int N, int K, int kLen) {
  __shared__ u16 As[128 * 32];
  __shared__ u16 Bs[128 * 32];
  const int tid = threadIdx.x;
  const int w = tid >> 6, l = tid & 63;
  const int row0 = blockIdx.y * 128, col0 = blockIdx.x * 128;
  const int kbeg = blockIdx.z * kLen, kend = kbeg + kLen;
  float* Pz = P + (size_t)blockIdx.z * S_TOT * N;
  const int wr = (w >> 1) * 64, wc = (w & 1) * 64;
  const int am = l & 15, ak = (l >> 4) * 8;
  const int srow = l >> 2, scol = (l & 3) * 8;

  f32x4 acc[4][4] = {};

  const u16* Abase = A + (size_t)(row0 + srow) * K + scol;
  const u16* Bbase = Bt + (size_t)(col0 + srow) * K + scol;
  const int R0 = (w * 2) * 16, R1 = (w * 2 + 1) * 16;

  for (int k0 = kbeg; k0 < kend; k0 += 32) {
    gld_lds16(Abase + (size_t)R0 * K + k0, &As[R0 * 32]);
    gld_lds16(Abase + (size_t)R1 * K + k0, &As[R1 * 32]);
    gld_lds16(Bbase + (size_t)R0 * K + k0, &Bs[R0 * 32]);
    gld_lds16(Bbase + (size_t)R1 * K + k0, &Bs[R1 * 32]);
    __syncthreads();
    bf16x8 af[4], bfr[4];
#pragma unroll
    for (int i = 0; i < 4; ++i) af[i] = *(const bf16x8*)&As[(wr + i * 16 + am) * 32 + ak];
#pragma unroll
    for (int j = 0; j < 4; ++j) bfr[j] = *(const bf16x8*)&Bs[(wc + j * 16 + am) * 32 + ak];
#pragma unroll
    for (int i = 0; i < 4; ++i)
#pragma unroll
      for (int j = 0; j < 4; ++j)
        acc[i][j] = __builtin_amdgcn_mfma_f32_16x16x32_bf16(af[i], bfr[j], acc[i][j], 0, 0, 0);
    __syncthreads();
  }

  const int rb = wr + (l >> 4) * 4;
  const int cb = wc + (l & 15);
#pragma unroll
  for (int i = 0; i < 4; ++i)
#pragma unroll
    for (int j = 0; j < 4; ++j) {
      const int colg = col0 + cb + j * 16;
#pragma unroll
      for (int r = 0; r < 4; ++r) {
        const int rowg = row0 + rb + i * 16 + r;
        Pz[(size_t)rowg * N + colg] = acc[i][j][r];
      }
    }
}

// ---------------- acc[i] += p1[i] + resid[i]  (O-proj split-K reduce) -------
__global__ __launch_bounds__(256)
void add3_kernel(float* __restrict__ acc, const float* __restrict__ p1,
                 const float* __restrict__ resid) {
  const size_t i = ((size_t)blockIdx.x * 256 + threadIdx.x) * 4;
  float4 a = *(const float4*)(acc + i);
  float4 b = *(const float4*)(p1 + i);
  float4 c = *(const float4*)(resid + i);
  a.x += b.x + c.x; a.y += b.y + c.y; a.z += b.z + c.z; a.w += b.w + c.w;
  *(float4*)(acc + i) = a;
}

// ---------------- down split-K reduce + residual + gated scatter ------------
// val = P0 + P1 + x1  (= x2);  out[b,t] = hs[b,t] + (val - hs[b,t]) * gate[s]
__global__ __launch_bounds__(256)
void down_finish_kernel(const float* __restrict__ P, const float* __restrict__ x1,
                        const int* __restrict__ tidx, const float* __restrict__ gate,
                        const float* __restrict__ hs, float* __restrict__ out) {
  const int s = blockIdx.x;
  const int b = s >> 10;
  const int t = tidx[s];
  const float gg = gate[s];
  const size_t src = (size_t)s * D_DIM;
  const size_t dst = ((size_t)b * T_LEN + t) * D_DIM;
  const size_t plane = (size_t)S_TOT * D_DIM;
  for (int d = threadIdx.x * 4; d < D_DIM; d += 1024) {
    float4 p0 = *(const float4*)(P + src + d);
    float4 p1 = *(const float4*)(P + plane + src + d);
    float4 xr = *(const float4*)(x1 + src + d);
    float4 hv = *(const float4*)(hs + dst + d);
    float4 r;
    r.x = hv.x + (p0.x + p1.x + xr.x - hv.x) * gg;
    r.y = hv.y + (p0.y + p1.y + xr.y - hv.y) * gg;
    r.z = hv.z + (p0.z + p1.z + xr.z - hv.z) * gg;
    r.w = hv.w + (p0.w + p1.w + xr.w - hv.w) * gg;
    *(float4*)(out + dst + d) = r;
  }
}

// ---------------- RoPE in place on bf16 qkv buffer [S, 6144] ----------------
__global__ __launch_bounds__(256)
void rope_kernel(u16* __restrict__ qkv, const float* __restrict__ cosb,
                 const float* __restrict__ sinb, const int* __restrict__ tidx) {
  const int idx = blockIdx.x * 256 + threadIdx.x;  // < S*H*64
  const int d = idx & 63;
  const int h = (idx >> 6) & 15;
  const int s = idx >> 10;
  const int b = s >> 10;
  const int t = tidx[s];
  const size_t base = (size_t)s * QKV_N + h * 128 + d;
  const size_t cb = ((size_t)b * T_LEN + t) * HD_DIM + d;
  const float c1 = cosb[cb], sn1 = sinb[cb];
  const float c2 = cosb[cb + 64], sn2 = sinb[cb + 64];
  float x1v, x2v;
  x1v = bf2f(qkv[base]); x2v = bf2f(qkv[base + 64]);
  qkv[base] = f2bf(x1v * c1 - x2v * sn1);
  qkv[base + 64] = f2bf(x2v * c2 + x1v * sn2);
  x1v = bf2f(qkv[base + 2048]); x2v = bf2f(qkv[base + 2048 + 64]);
  qkv[base + 2048] = f2bf(x1v * c1 - x2v * sn1);
  qkv[base + 2048 + 64] = f2bf(x2v * c2 + x1v * sn2);
}

// ---------------- MFMA flash attention (8 waves, 2 kv-groups) ---------------
// grid (32, H); block 512 (8 waves).  h<8: qt=31-bx, h>=8: qt=bx  (so block
// ids i and i+256 -- which land on the same CU under round-robin dispatch --
// carry complementary work).  Waves 0-3 = group 0 (even kv tiles), waves
// 4-7 = group 1 (odd kv tiles); in-LDS (m,l,O) merge at the end.
// V comes pre-transposed (VT[h*128+d][s]); K/V staged with global_load_lds
// into XOR-swizzled LDS (linear dest, inverse-swizzled per-lane source).
// LDS = 64 KiB exactly: Ps aliases the first half of Ks (safe: an extra
// block barrier separates the last Ks read (QK^T) from the first Ps write).
__global__ __launch_bounds__(512, 4)
void attn_mfma_kernel(const u16* __restrict__ QKV, const u16* __restrict__ VT,
                      u16* __restrict__ Og) {
  const int h  = blockIdx.y;
  const int bx = blockIdx.x;
  const int qt = (h < 8) ? (31 - bx) : bx;
  const int q0 = qt * 64;
  const int tid = threadIdx.x;
  const int l  = tid & 63;
  const int w  = tid >> 6;       // 0..7
  const int g  = w >> 2;         // kv group
  const int wq = w & 3;          // q sub-block (16 rows)
  const int lm = l & 15, lk = l >> 4;

  __shared__ __align__(16) unsigned char smem[65536];
  u16* Ks = (u16*)(smem + g * 16384);           // [64 kv][128 d]  swizzled
  u16* Vt = (u16*)(smem + 32768 + g * 16384);   // [128 d][64 kv]  swizzled
  u16* Ps = (u16*)(smem + g * 16384);           // [64 q][64 kv]   aliases Ks

  const u16* Qg  = QKV + h * 128;
  const u16* Kg  = QKV + 2048 + h * 128;
  const u16* Vgt = VT + (size_t)h * 128 * S_TOT;

  // Q fragments: rows q0 + wq*16 + lm, k-chunks of 32 over d=128
  bf16x8 qf[4];
  {
    const u16* qrow = Qg + (size_t)(q0 + wq * 16 + lm) * QKV_N;
#pragma unroll
    for (int ks = 0; ks < 4; ++ks) qf[ks] = *(const bf16x8*)&qrow[ks * 32 + lk * 8];
  }

  // per-lane inverse-swizzled staging source offsets (u16 units in-plane).
  // chunk ci = (wq*4+p)*64 + l ; LDS gets linear base + lane*16.
  int ksrc[4], vsrc[4];
#pragma unroll
  for (int p = 0; p < 4; ++p) {
    const int ci = (wq * 4 + p) * 64 + l;
    const int kr = ci >> 4, kc = ci & 15;        // K: row=kv (0..63), 16 chunks/row
    ksrc[p] = kr * QKV_N + ((kc ^ (kr & 7)) * 8);
    const int vr = ci >> 3, vc = ci & 7;         // V^T: row=d (0..127), 8 chunks/row
    vsrc[p] = vr * S_TOT + ((vc ^ (vr & 7)) * 8);
  }

  f32x4 oacc[8];
#pragma unroll
  for (int n = 0; n < 8; ++n) oacc[n] = (f32x4){0.f, 0.f, 0.f, 0.f};
  float m_run[4] = {-1e30f, -1e30f, -1e30f, -1e30f};
  float l_run[4] = {0.f, 0.f, 0.f, 0.f};

  const int ntiles = (g == 0) ? (qt / 2 + 1) : ((qt + 1) / 2);  // my kv tiles
  const int nmax = qt / 2 + 1;                                   // uniform trip
  const float scale = 0.08838834764831845f;  // 1/sqrt(128)

  for (int it = 0; it < nmax; ++it) {
    const int kt = g + 2 * it;
    const int kv0 = kt * 64;
    const bool active = (it < ntiles);
    __syncthreads();                     // previous tile fully consumed
    if (active) {
#pragma unroll
      for (int p = 0; p < 4; ++p) {
        gld_lds16(Kg + (size_t)kv0 * QKV_N + ksrc[p], &Ks[(wq * 4 + p) * 512]);
        gld_lds16(Vgt + kv0 + vsrc[p],               &Vt[(wq * 4 + p) * 512]);
      }
    }
    __syncthreads();                     // staging visible

    f32x4 sacc[4];
    if (active) {
      // QK^T: S[16q x 64kv] per wave
#pragma unroll
      for (int j = 0; j < 4; ++j) sacc[j] = (f32x4){0.f, 0.f, 0.f, 0.f};
#pragma unroll
      for (int j = 0; j < 4; ++j) {
        const int row = j * 16 + lm;
#pragma unroll
        for (int ks = 0; ks < 4; ++ks) {
          const int c = ks * 4 + lk;
          const bf16x8 kf = *(const bf16x8*)&(
              (const unsigned char*)Ks)[row * 256 + ((c ^ (row & 7)) << 4)];
          sacc[j] = __builtin_amdgcn_mfma_f32_16x16x32_bf16(qf[ks], kf, sacc[j], 0, 0, 0);
        }
      }
    }
    __syncthreads();                     // all Ks reads done; Ps may overwrite

    if (active) {
      // mask + online softmax (in registers, per 16-lane group)
      float mx[4] = {-1e30f, -1e30f, -1e30f, -1e30f};
#pragma unroll
      for (int j = 0; j < 4; ++j) {
        const int colg = kv0 + j * 16 + lm;
#pragma unroll
        for (int r = 0; r < 4; ++r) {
          const int rowg = q0 + wq * 16 + lk * 4 + r;
          float s = sacc[j][r] * scale;
          s = (colg > rowg) ? -1e30f : s;
          sacc[j][r] = s;
          mx[r] = fmaxf(mx[r], s);
        }
      }
#pragma unroll
      for (int r = 0; r < 4; ++r)
#pragma unroll
        for (int dlt = 1; dlt < 16; dlt <<= 1)
          mx[r] = fmaxf(mx[r], __shfl_xor(mx[r], dlt));
      float alpha[4];
#pragma unroll
      for (int r = 0; r < 4; ++r) {
        const float mnew = fmaxf(m_run[r], mx[r]);
        const float al = __expf(m_run[r] - mnew);
        float sum = 0.f;
#pragma unroll
        for (int j = 0; j < 4; ++j) {
          const float pe = __expf(sacc[j][r] - mnew);
          sacc[j][r] = pe;
          sum += pe;
        }
#pragma unroll
        for (int dlt = 1; dlt < 16; dlt <<= 1) sum += __shfl_xor(sum, dlt);
        l_run[r] = l_run[r] * al + sum;
        m_run[r] = mnew;
        alpha[r] = al;
      }
#pragma unroll
      for (int n = 0; n < 8; ++n)
#pragma unroll
        for (int r = 0; r < 4; ++r) oacc[n][r] *= alpha[r];

      // P (C-layout) -> Ps (A-layout, swizzled); wave-local rows
#pragma unroll
      for (int j = 0; j < 4; ++j)
#pragma unroll
        for (int r = 0; r < 4; ++r) {
          const int row = wq * 16 + lk * 4 + r;
          *(u16*)&((unsigned char*)Ps)[row * 128 +
              (((j * 16 + lm) * 2) ^ ((row & 7) << 4))] = f2bf(sacc[j][r]);
        }

      // PV: O[16q x 128d] += P[16 x 64] * V[64 x 128]
#pragma unroll
      for (int ks2 = 0; ks2 < 2; ++ks2) {
        const int prow = wq * 16 + lm;
        const bf16x8 pf = *(const bf16x8*)&(
            (const unsigned char*)Ps)[prow * 128 +
                ((ks2 * 64 + lk * 16) ^ ((prow & 7) << 4))];
#pragma unroll
        for (int n = 0; n < 8; ++n) {
          const int vrow = n * 16 + lm;
          const int vc = ks2 * 4 + lk;
          const bf16x8 vf = *(const bf16x8*)&(
              (const unsigned char*)Vt)[vrow * 128 + ((vc ^ (vrow & 7)) << 4)];
          oacc[n] = __builtin_amdgcn_mfma_f32_16x16x32_bf16(pf, vf, oacc[n], 0, 0, 0);
        }
      }
    }
  }

  // ---- merge the two kv-groups via LDS (reuses staging space) ----
  __syncthreads();
  float* Obuf = (float*)smem;              // [64][132] f32 (padded)
  float* Mbuf = (float*)(smem + 33792);    // [64]
  float* Lbuf = (float*)(smem + 34048);    // [64]
  if (g == 1) {
#pragma unroll
    for (int r = 0; r < 4; ++r) {
      const int row = wq * 16 + lk * 4 + r;
      if (lm == 0) { Mbuf[row] = m_run[r]; Lbuf[row] = l_run[r]; }
#pragma unroll
      for (int n = 0; n < 8; ++n) Obuf[row * 132 + n * 16 + lm] = oacc[n][r];
    }
  }
  __syncthreads();
  if (g == 0) {
    float a0[4], a1[4], linv[4];
#pragma unroll
    for (int r = 0; r < 4; ++r) {
      const int row = wq * 16 + lk * 4 + r;
      const float m1 = Mbuf[row], l1 = Lbuf[row];
      const float M = fmaxf(m_run[r], m1);
      a0[r] = __expf(m_run[r] - M);
      a1[r] = __expf(m1 - M);
      linv[r] = 1.f / (a0[r] * l_run[r] + a1[r] * l1);
    }
#pragma unroll
    for (int n = 0; n < 8; ++n)
#pragma unroll
      for (int r = 0; r < 4; ++r) {
        const int row = wq * 16 + lk * 4 + r;
        const float o = (oacc[n][r] * a0[r] +
                         Obuf[row * 132 + n * 16 + lm] * a1[r]) * linv[r];
        Og[(size_t)(q0 + row) * 2048 + h * 128 + n * 16 + lm] = f2bf(o);
      }
  }
}

// ---------------- silu(gate)*up on fused bf16 gu buffer ---------------------
__global__ __launch_bounds__(256)
void silu_mul_kernel(const u16* __restrict__ gu, u16* __restrict__ out) {
  const size_t i = (size_t)blockIdx.x * 256 + threadIdx.x;  // 4-elem units
  const int s = (int)(i / 1408);
  const int c = (int)(i - (size_t)s * 1408);
  const uint2 g4 = *(const uint2*)&gu[(size_t)s * GU_N + c * 4];
  const uint2 u4 = *(const uint2*)&gu[(size_t)s * GU_N + I_DIM + c * 4];
  float g[4], u[4];
  g[0] = __uint_as_float(g4.x << 16); g[1] = __uint_as_float(g4.x & 0xffff0000u);
  g[2] = __uint_as_float(g4.y << 16); g[3] = __uint_as_float(g4.y & 0xffff0000u);
  u[0] = __uint_as_float(u4.x << 16); u[1] = __uint_as_float(u4.x & 0xffff0000u);
  u[2] = __uint_as_float(u4.y << 16); u[3] = __uint_as_float(u4.y & 0xffff0000u);
  u16 r[4];
#pragma unroll
  for (int j = 0; j < 4; ++j) r[j] = f2bf(g[j] * u[j] / (1.f + __expf(-g[j])));
  u32 a0 = (u32)r[0] | ((u32)r[1] << 16);
  u32 a1 = (u32)r[2] | ((u32)r[3] << 16);
  *(uint2*)&out[(size_t)s * I_DIM + c * 4] = make_uint2(a0, a1);
}

// ---------------------------------------------------------------------------
extern "C" void kernel_launch(void* const* d_in, const int* in_sizes, int n_in,
                              void* d_out, int out_size, void* d_ws, size_t ws_size,
                              hipStream_t stream) {
  (void)in_sizes; (void)n_in; (void)out_size; (void)ws_size;
  const float* hs    = (const float*)d_in[0];
  const float* orig  = (const float*)d_in[1];
  const float* post  = (const float*)d_in[2];
  const float* prior = (const float*)d_in[3];
  const float* cosb  = (const float*)d_in[4];
  const float* sinb  = (const float*)d_in[5];
  const float* q_w = (const float*)d_in[7];
  const float* q_b = (const float*)d_in[8];
  const float* k_w = (const float*)d_in[9];
  const float* k_b = (const float*)d_in[10];
  const float* v_w = (const float*)d_in[11];
  const float* v_b = (const float*)d_in[12];
  const float* o_w = (const float*)d_in[13];
  const float* ln1 = (const float*)d_in[14];
  const float* ln2 = (const float*)d_in[15];
  const float* gate_w = (const float*)d_in[16];
  const float* up_w   = (const float*)d_in[17];
  const float* down_w = (const float*)d_in[18];
  const float* beta_ce = (const float*)d_in[19];
  const float* beta_cu = (const float*)d_in[20];
  const float* ce_off  = (const float*)d_in[21];
  float* out = (float*)d_out;

  char* wsp = (char*)d_ws;
  size_t off = 0;
  auto alloc = [&](size_t n) -> char* {
    char* r = wsp + off; off += (n + 255) & ~(size_t)255; return r;
  };
  const size_t SD4 = (size_t)S_TOT * D_DIM * 4;   // 16 MB

  float* scores  = (float*)alloc((size_t)B_DIM * T_LEN * 4);
  int*   rnk     = (int*)  alloc((size_t)B_DIM * T_LEN * 4);
  int*   tidx    = (int*)  alloc((size_t)S_TOT * 4);
  float* gatebuf = (float*)alloc((size_t)S_TOT * 4);
  float* qkvbias = (float*)alloc((size_t)QKV_N * 4);
  u16* qkvwt = (u16*)alloc((size_t)QKV_N * 2048 * 2);       // 25.2 MB
  u16* owt   = (u16*)alloc((size_t)2048 * 2048 * 2);        //  8.4 MB
  u16* guwt  = (u16*)alloc((size_t)GU_N * 2048 * 2);        // 46.1 MB
  u16* dwt   = (u16*)alloc((size_t)2048 * I_DIM * 2);       // 23.1 MB
  // region A: selh (rms1..O-proj) then h2 (rms2..gate/up)
  char* rA = alloc(SD4);
  float* selh = (float*)rA;
  u16*   h2   = (u16*)rA;
  // region B: h1 (rms1..QKV) then o_attn (attn..O-proj) then mlp_in (silu..down)
  char* rB = alloc((size_t)S_TOT * I_DIM * 2);              // 23.1 MB
  u16* h1     = (u16*)rB;
  u16* o_attn = (u16*)rB;
  u16* mlp_in = (u16*)rB;
  // region C: qkv_bf (QKV..attn) then gu_bf (gate/up..silu) then down-partials
  char* rC = alloc((size_t)S_TOT * GU_N * 2);               // 44 MB
  u16* qkv_bf = (u16*)rC;
  u16* gu_bf  = (u16*)rC;
  float* dpart = (float*)rC;   // 2 x [S,D] f32 partial planes (33.6 MB)
  // x1 (16.8 MB) + adjacent scratch plane (16.8 MB) for O-proj split-K
  float* x1  = (float*)alloc(SD4);
  float* x1p = (float*)alloc(SD4);   // contiguous with x1: plane 1
  (void)x1p;
  // vT (pre-transposed V, 8 MB) lives in x1 -- x1 is only written at step 7,
  // after attention has consumed vT.
  u16* vT = (u16*)x1;

  // 0) output starts as a copy of hidden_states; fused qkv bias
  hipMemcpyAsync(out, hs, (size_t)B_DIM * T_LEN * D_DIM * 4,
                 hipMemcpyDeviceToDevice, stream);
  hipMemcpyAsync(qkvbias, q_b, 2048 * 4, hipMemcpyDeviceToDevice, stream);
  hipMemcpyAsync(qkvbias + 2048, k_b, 2048 * 4, hipMemcpyDeviceToDevice, stream);
  hipMemcpyAsync(qkvbias + 4096, v_b, 2048 * 4, hipMemcpyDeviceToDevice, stream);

  // 1) router scores + top-k selection (temporal order)
  router_kernel<<<dim3(B_DIM * T_LEN), 256, 0, stream>>>(orig, post, prior,
                                                         beta_ce, beta_cu, ce_off, scores);
  rank_kernel<<<dim3(8, B_DIM), 256, 0, stream>>>(scores, rnk);
  compact_kernel<<<dim3(B_DIM), 256, 0, stream>>>(scores, rnk, tidx, gatebuf);

  // 2) weight conversions (transpose to [N][K] bf16); fused layouts
  transpose_bf16_kernel<<<dim3(64, 64), 256, 0, stream>>>(q_w, qkvwt, 2048, 2048);
  transpose_bf16_kernel<<<dim3(64, 64), 256, 0, stream>>>(k_w, qkvwt + (size_t)2048 * 2048, 2048, 2048);
  transpose_bf16_kernel<<<dim3(64, 64), 256, 0, stream>>>(v_w, qkvwt + (size_t)4096 * 2048, 2048, 2048);
  transpose_bf16_kernel<<<dim3(64, 64), 256, 0, stream>>>(o_w, owt, 2048, 2048);
  transpose_bf16_kernel<<<dim3(176, 64), 256, 0, stream>>>(gate_w, guwt, 2048, I_DIM);
  transpose_bf16_kernel<<<dim3(176, 64), 256, 0, stream>>>(up_w, guwt + (size_t)I_DIM * 2048, 2048, I_DIM);
  transpose_bf16_kernel<<<dim3(64, 176), 256, 0, stream>>>(down_w, dwt, I_DIM, 2048);

  // 3) gather + rmsnorm1 -> selh (f32), h1 (bf16)
  rmsnorm_kernel<<<dim3(S_TOT), 256, 0, stream>>>(hs, tidx, ln1, selh, h1);

  // 4) fused QKV GEMM -> qkv_bf (bf16, [S][6144])
  gemm_bf16_kernel<<<dim3(48, 16), 256, 0, stream>>>(h1, qkvwt, nullptr, qkv_bf,
                                                     qkvbias, nullptr, QKV_N, 2048);
  // 5) RoPE in place (q & k halves)
  rope_kernel<<<dim3((S_TOT * H_NUM * 64) / 256), 256, 0, stream>>>(qkv_bf, cosb, sinb, tidx);

  // 5b) pre-transpose V -> vT[h*128+d][s]
  vtrans_kernel<<<dim3(64, 64), 256, 0, stream>>>(qkv_bf, vT);

  // 6) MFMA flash attention -> o_attn (bf16)
  attn_mfma_kernel<<<dim3(32, H_NUM), 512, 0, stream>>>(qkv_bf, vT, o_attn);

  // 7) O-proj split-K=2 -> planes {x1, x1+SD}; reduce (+selh resid) -> x1
  gemm_bf16_splitk_kernel<<<dim3(16, 16, 2), 256, 0, stream>>>(o_attn, owt, x1,
                                                               2048, 2048, 1024);
  add3_kernel<<<dim3((S_TOT * D_DIM) / 1024), 256, 0, stream>>>(
      x1, x1 + (size_t)S_TOT * D_DIM, selh);

  // 8) rmsnorm2 -> h2 (bf16)
  rmsnorm_kernel<<<dim3(S_TOT), 256, 0, stream>>>(x1, nullptr, ln2, nullptr, h2);

  // 9) fused gate/up GEMM -> gu_bf (bf16, [S][11264])
  gemm_bf16_kernel<<<dim3(88, 16), 256, 0, stream>>>(h2, guwt, nullptr, gu_bf,
                                                     nullptr, nullptr, GU_N, 2048);

  // 10) silu * up -> mlp_in (bf16)
  silu_mul_kernel<<<dim3((S_TOT * (I_DIM / 4)) / 256), 256, 0, stream>>>(gu_bf, mlp_in);

  // 11) down split-K=2 -> planes {rC, rC+SD} (gu_bf dead after silu_mul)
  gemm_bf16_splitk_kernel<<<dim3(16, 16, 2), 256, 0, stream>>>(mlp_in, dwt, dpart,
                                                               2048, 5632, 2816);

  // 12) fused reduce + residual(x1) + gated scatter into out
  down_finish_kernel<<<dim3(S_TOT), 256, 0, stream>>>(dpart, x1, tidx, gatebuf,
                                                      hs, out);
}

// Round 4
// 921.187 us; speedup vs baseline: 1.1760x; 1.0021x over previous
//
#include <hip/hip_runtime.h>

// ---------------------------------------------------------------------------
// DTFDynamicLayer: router top-k gather -> Qwen2 block (bf16 MFMA GEMMs,
// MFMA flash attention) -> gated scatter.  B=2,T=2048,D=2048,H=16,HD=128,
// I=5632, K=1024, S=2048.  All fixed at compile time.
// ---------------------------------------------------------------------------

typedef unsigned short u16;
typedef unsigned int u32;
typedef short bf16x8 __attribute__((ext_vector_type(8)));
typedef float f32x4 __attribute__((ext_vector_type(4)));

#define T_LEN 2048
#define D_DIM 2048
#define B_DIM 2
#define H_NUM 16
#define HD_DIM 128
#define I_DIM 5632
#define K_CAP 1024
#define S_TOT 2048
#define QKV_N 6144
#define GU_N 11264

__device__ __forceinline__ u16 f2bf(float f) {
  union { float f; u32 u; } a; a.f = f;
  u32 r = a.u + 0x7fffu + ((a.u >> 16) & 1u);
  return (u16)(r >> 16);
}
__device__ __forceinline__ float bf2f(u16 x) {
  return __uint_as_float((u32)x << 16);
}

__device__ __forceinline__ void gld_lds16(const void* g, void* l) {
  void* gg = const_cast<void*>(g);
  __builtin_amdgcn_global_load_lds(
      (__attribute__((address_space(1))) u32*)gg,
      (__attribute__((address_space(3))) u32*)l, 16, 0, 0);
}

// ---------------- router: scores[b,t] = bcu*||o-p|| + bce*(||p-pr||+off) ----
__global__ __launch_bounds__(256)
void router_kernel(const float* __restrict__ orig, const float* __restrict__ post,
                   const float* __restrict__ prior, const float* __restrict__ bce,
                   const float* __restrict__ bcu, const float* __restrict__ coff,
                   float* __restrict__ scores) {
  const int row = blockIdx.x;
  const size_t base = (size_t)row * D_DIM;
  float s1 = 0.f, s2 = 0.f;
  for (int d = threadIdx.x * 4; d < D_DIM; d += 1024) {
    float4 o = *(const float4*)(orig + base + d);
    float4 p = *(const float4*)(post + base + d);
    float4 r = *(const float4*)(prior + base + d);
    float a;
    a = o.x - p.x; s1 += a * a;  a = o.y - p.y; s1 += a * a;
    a = o.z - p.z; s1 += a * a;  a = o.w - p.w; s1 += a * a;
    a = p.x - r.x; s2 += a * a;  a = p.y - r.y; s2 += a * a;
    a = p.z - r.z; s2 += a * a;  a = p.w - r.w; s2 += a * a;
  }
#pragma unroll
  for (int k = 32; k; k >>= 1) { s1 += __shfl_down(s1, k); s2 += __shfl_down(s2, k); }
  __shared__ float r1[4], r2[4];
  const int wv = threadIdx.x >> 6;
  if ((threadIdx.x & 63) == 0) { r1[wv] = s1; r2[wv] = s2; }
  __syncthreads();
  if (threadIdx.x == 0) {
    float cu = sqrtf(r1[0] + r1[1] + r1[2] + r1[3]);
    float ce = sqrtf(r2[0] + r2[1] + r2[2] + r2[3]);
    scores[row] = bcu[0] * cu + bce[0] * (ce + coff[0]);
  }
}

// ---------------- rank: stable top-k rank (matches lax.top_k tie-break) -----
__global__ __launch_bounds__(256)
void rank_kernel(const float* __restrict__ scores, int* __restrict__ rnk) {
  const int b = blockIdx.y;
  const int t = blockIdx.x * 256 + threadIdx.x;
  __shared__ float s[T_LEN];
  for (int u = threadIdx.x; u < T_LEN; u += 256) s[u] = scores[b * T_LEN + u];
  __syncthreads();
  const float st = s[t];
  int r = 0;
  for (int u = 0; u < T_LEN; ++u) {
    float su = s[u];
    r += ((su > st) || (su == st && u < t)) ? 1 : 0;
  }
  rnk[b * T_LEN + t] = r;
}

// ---------------- compact: selected (rank<K) in temporal order --------------
__global__ __launch_bounds__(256)
void compact_kernel(const float* __restrict__ scores, const int* __restrict__ rnk,
                    int* __restrict__ tidx, float* __restrict__ gate) {
  const int b = blockIdx.x;
  const int base = b * T_LEN;
  __shared__ int csum[256];
  int f[8]; int loc = 0;
  const int t0 = threadIdx.x * 8;
#pragma unroll
  for (int i = 0; i < 8; ++i) { f[i] = (rnk[base + t0 + i] < K_CAP) ? 1 : 0; loc += f[i]; }
  csum[threadIdx.x] = loc;
  __syncthreads();
  if (threadIdx.x == 0) {
    int run = 0;
    for (int i = 0; i < 256; ++i) { int tmp = csum[i]; csum[i] = run; run += tmp; }
  }
  __syncthreads();
  int pos = csum[threadIdx.x];
#pragma unroll
  for (int i = 0; i < 8; ++i) {
    if (f[i]) {
      float sc = scores[base + t0 + i];
      tidx[b * K_CAP + pos] = t0 + i;
      gate[b * K_CAP + pos] = 1.f / (1.f + __expf(-sc));
      ++pos;
    }
  }
}

// ---------------- weight transpose + bf16 convert: Wt[n][k] = W[k][n] -------
__global__ __launch_bounds__(256)
void transpose_bf16_kernel(const float* __restrict__ W, u16* __restrict__ Wt,
                           int K, int N) {
  __shared__ float tile[32][33];
  const int bn = blockIdx.x * 32, bk = blockIdx.y * 32;
  const int tx = threadIdx.x & 31, ty = threadIdx.x >> 5;
#pragma unroll
  for (int i = 0; i < 32; i += 8)
    tile[ty + i][tx] = W[(size_t)(bk + ty + i) * N + bn + tx];
  __syncthreads();
#pragma unroll
  for (int i = 0; i < 32; i += 8)
    Wt[(size_t)(bn + ty + i) * K + bk + tx] = f2bf(tile[tx][ty + i]);
}

// ---------------- V pre-transpose: qkv[s][4096+c] -> VT[c][s] (bf16) --------
__global__ __launch_bounds__(256)
void vtrans_kernel(const u16* __restrict__ qkv, u16* __restrict__ VT) {
  __shared__ u16 tile[32][34];
  const int s0 = blockIdx.x * 32;
  const int c0 = blockIdx.y * 32;
  const int tx = threadIdx.x & 31, ty = threadIdx.x >> 5;
#pragma unroll
  for (int i = 0; i < 32; i += 8)
    tile[ty + i][tx] = qkv[(size_t)(s0 + ty + i) * QKV_N + 4096 + c0 + tx];
  __syncthreads();
#pragma unroll
  for (int i = 0; i < 32; i += 8)
    VT[(size_t)(c0 + ty + i) * S_TOT + s0 + tx] = tile[tx][ty + i];
}

// ---------------- rmsnorm (optional gather, optional f32 copy, bf16 out) ----
__global__ __launch_bounds__(256)
void rmsnorm_kernel(const float* __restrict__ X, const int* __restrict__ tidx,
                    const float* __restrict__ w, float* __restrict__ xcopy,
                    u16* __restrict__ Y) {
  const int s = blockIdx.x;
  const float* row;
  if (tidx) {
    const int b = s >> 10;
    const int t = tidx[s];
    row = X + ((size_t)b * T_LEN + t) * D_DIM;
  } else {
    row = X + (size_t)s * D_DIM;
  }
  const int d0 = threadIdx.x * 4;
  float4 v0 = *(const float4*)(row + d0);
  float4 v1 = *(const float4*)(row + d0 + 1024);
  float ss = v0.x*v0.x + v0.y*v0.y + v0.z*v0.z + v0.w*v0.w
           + v1.x*v1.x + v1.y*v1.y + v1.z*v1.z + v1.w*v1.w;
#pragma unroll
  for (int k = 32; k; k >>= 1) ss += __shfl_down(ss, k);
  __shared__ float red[4];
  if ((threadIdx.x & 63) == 0) red[threadIdx.x >> 6] = ss;
  __syncthreads();
  const float tot = red[0] + red[1] + red[2] + red[3];
  const float rms = rsqrtf(tot * (1.0f / D_DIM) + 1e-6f);
  if (xcopy) {
    *(float4*)(xcopy + (size_t)s * D_DIM + d0) = v0;
    *(float4*)(xcopy + (size_t)s * D_DIM + d0 + 1024) = v1;
  }
  const float4 w0 = *(const float4*)(w + d0);
  const float4 w1 = *(const float4*)(w + d0 + 1024);
  u16* yp = Y + (size_t)s * D_DIM;
  u32 a0 = (u32)f2bf(v0.x * rms * w0.x) | ((u32)f2bf(v0.y * rms * w0.y) << 16);
  u32 a1 = (u32)f2bf(v0.z * rms * w0.z) | ((u32)f2bf(v0.w * rms * w0.w) << 16);
  *(uint2*)(yp + d0) = make_uint2(a0, a1);
  u32 b0 = (u32)f2bf(v1.x * rms * w1.x) | ((u32)f2bf(v1.y * rms * w1.y) << 16);
  u32 b1 = (u32)f2bf(v1.z * rms * w1.z) | ((u32)f2bf(v1.w * rms * w1.w) << 16);
  *(uint2*)(yp + d0 + 1024) = make_uint2(b0, b1);
}

// ---------------- bf16 MFMA GEMM, m97 structure (kept for split-K uses) -----
__global__ __launch_bounds__(256)
void gemm_bf16_kernel(const u16* __restrict__ A, const u16* __restrict__ Bt,
                      float* __restrict__ C, u16* __restrict__ Cbf,
                      const float* __restrict__ bias,
                      const float* __restrict__ resid, int N, int K) {
  __shared__ u16 As[128 * 32];
  __shared__ u16 Bs[128 * 32];
  const int tid = threadIdx.x;
  const int w = tid >> 6, l = tid & 63;
  const int row0 = blockIdx.y * 128, col0 = blockIdx.x * 128;
  const int wr = (w >> 1) * 64, wc = (w & 1) * 64;
  const int am = l & 15, ak = (l >> 4) * 8;
  const int srow = l >> 2, scol = (l & 3) * 8;

  f32x4 acc[4][4] = {};

  const u16* Abase = A + (size_t)(row0 + srow) * K + scol;
  const u16* Bbase = Bt + (size_t)(col0 + srow) * K + scol;
  const int R0 = (w * 2) * 16, R1 = (w * 2 + 1) * 16;

  for (int k0 = 0; k0 < K; k0 += 32) {
    gld_lds16(Abase + (size_t)R0 * K + k0, &As[R0 * 32]);
    gld_lds16(Abase + (size_t)R1 * K + k0, &As[R1 * 32]);
    gld_lds16(Bbase + (size_t)R0 * K + k0, &Bs[R0 * 32]);
    gld_lds16(Bbase + (size_t)R1 * K + k0, &Bs[R1 * 32]);
    __syncthreads();
    bf16x8 af[4], bfr[4];
#pragma unroll
    for (int i = 0; i < 4; ++i) af[i] = *(const bf16x8*)&As[(wr + i * 16 + am) * 32 + ak];
#pragma unroll
    for (int j = 0; j < 4; ++j) bfr[j] = *(const bf16x8*)&Bs[(wc + j * 16 + am) * 32 + ak];
#pragma unroll
    for (int i = 0; i < 4; ++i)
#pragma unroll
      for (int j = 0; j < 4; ++j)
        acc[i][j] = __builtin_amdgcn_mfma_f32_16x16x32_bf16(af[i], bfr[j], acc[i][j], 0, 0, 0);
    __syncthreads();
  }

  const int rb = wr + (l >> 4) * 4;
  const int cb = wc + (l & 15);
#pragma unroll
  for (int i = 0; i < 4; ++i) {
#pragma unroll
    for (int j = 0; j < 4; ++j) {
      const int colg = col0 + cb + j * 16;
      const float bv = bias ? bias[colg] : 0.0f;
#pragma unroll
      for (int r = 0; r < 4; ++r) {
        const int rowg = row0 + rb + i * 16 + r;
        const size_t idx = (size_t)rowg * N + colg;
        float v = acc[i][j][r] + bv;
        if (resid) v += resid[idx];
        if (Cbf) Cbf[idx] = f2bf(v);
        else C[idx] = v;
      }
    }
  }
}

// ---------------- 8-phase-style 256x256 bf16 GEMM (BK=32, 64 KiB LDS) -------
// C = A[M,K] x Bt[N,K]^T (+bias), bf16 out.  512 threads = 8 waves (2M x 4N),
// per-wave output 128x64 (acc[8][4] f32x4).  Double-buffered K-tiles (BK=32);
// per K-tile 2 phases: {ds_read subtile + issue prefetch -> s_barrier ->
// lgkmcnt(0) -> setprio(1) -> 16 MFMA -> setprio(0) -> barrier}, counted
// vmcnt(2) only at K-tile boundaries (never 0 mid-loop).  LDS XOR-swizzle
// (granule ^= row&3) applied as inverse-swizzled global source (linear
// global_load_lds dest) + swizzled ds_read.  Requires NT >= 3.
__global__ __launch_bounds__(512, 2)
void gemm_bf16_8ph_kernel(const u16* __restrict__ A, const u16* __restrict__ Bt,
                          u16* __restrict__ Cbf, const float* __restrict__ bias,
                          int N, int K) {
  // layout: smem[buf][mat][half][128 rows][32 cols bf16]; 8 KiB per half.
  __shared__ __align__(16) unsigned char smem[65536];
  const int tid = threadIdx.x;
  const int l = tid & 63, w = tid >> 6;
  const int wm = w >> 2, wn = w & 3;
  const int lm = l & 15, lk = l >> 4;
  const int row0 = blockIdx.y * 256, col0 = blockIdx.x * 256;
  const int NT = K >> 5;

  // staging: per thread one 16B chunk per half-tile.  chunk ci = w*64+l;
  // LDS row sr = ci>>2, slot ci&3; holds global granule (ci&3)^(sr&3).
  const int ci = w * 64 + l;
  const int sr = ci >> 2;
  const int sg = (ci & 3) ^ (sr & 3);
  const u16* Ab = A + (size_t)row0 * K;
  const u16* Bb = Bt + (size_t)col0 * K;

  auto stage = [&](int buf, int mat, int half, int kt) {
    const u16* src = mat ? Bb : Ab;
    gld_lds16(src + (size_t)(half * 128 + sr) * K + kt * 32 + sg * 8,
              smem + (buf << 15) + (mat << 14) + (half << 13) + (w << 10));
  };

  f32x4 acc[8][4] = {};

  // prologue: A+B of kt0 -> buf0; B of kt1 -> buf1.  (A(kt1) staged in kt0-P0.)
  stage(0, 0, 0, 0); stage(0, 0, 1, 0); stage(0, 1, 0, 0); stage(0, 1, 1, 0);
  stage(1, 1, 0, 1); stage(1, 1, 1, 1);
  asm volatile("s_waitcnt vmcnt(2)" ::: "memory");
  __builtin_amdgcn_s_barrier();

  const int xo = ((lk << 4) ^ ((lm & 3) << 4));
  for (int kt = 0; kt < NT; ++kt) {
    const int buf = kt & 1;
    const unsigned char* ab = smem + (buf << 15) + (wm << 13);
    const unsigned char* bb = smem + (buf << 15) + 16384 + ((wn >> 1) << 13);
    const int brow = (wn & 1) * 64;
    bf16x8 afr[4], bfr[4];

    // ---- phase 0: rows 0..63 of wave's half ----
#pragma unroll
    for (int j = 0; j < 4; ++j)
      bfr[j] = *(const bf16x8*)(bb + (brow + j * 16 + lm) * 64 + xo);
#pragma unroll
    for (int i = 0; i < 4; ++i)
      afr[i] = *(const bf16x8*)(ab + (i * 16 + lm) * 64 + xo);
    if (kt + 1 < NT) {          // A(kt+1): buf^1 A slots dead since kt-1 end
      stage(buf ^ 1, 0, 0, kt + 1);
      stage(buf ^ 1, 0, 1, kt + 1);
    }
    __builtin_amdgcn_s_barrier();
    asm volatile("s_waitcnt lgkmcnt(0)" ::: "memory");
    __builtin_amdgcn_sched_barrier(0);
    __builtin_amdgcn_s_setprio(1);
#pragma unroll
    for (int i = 0; i < 4; ++i)
#pragma unroll
      for (int j = 0; j < 4; ++j)
        acc[i][j] = __builtin_amdgcn_mfma_f32_16x16x32_bf16(afr[i], bfr[j], acc[i][j], 0, 0, 0);
    __builtin_amdgcn_s_setprio(0);
    __builtin_amdgcn_s_barrier();

    // ---- phase 1: rows 64..127 ----
#pragma unroll
    for (int i = 0; i < 4; ++i)
      afr[i] = *(const bf16x8*)(ab + ((i + 4) * 16 + lm) * 64 + xo);
    if (kt + 2 < NT) {          // B(kt+2): buf B slots dead after phase 0
      stage(buf, 1, 0, kt + 2);
      stage(buf, 1, 1, kt + 2);
    }
    __builtin_amdgcn_s_barrier();
    asm volatile("s_waitcnt lgkmcnt(0)" ::: "memory");
    __builtin_amdgcn_sched_barrier(0);
    __builtin_amdgcn_s_setprio(1);
#pragma unroll
    for (int i = 0; i < 4; ++i)
#pragma unroll
      for (int j = 0; j < 4; ++j)
        acc[i + 4][j] = __builtin_amdgcn_mfma_f32_16x16x32_bf16(afr[i], bfr[j], acc[i + 4][j], 0, 0, 0);
    __builtin_amdgcn_s_setprio(0);
    if (kt + 1 < NT) {
      // ensure A(kt+1)+B(kt+1) landed; only B(kt+2) (2 loads) may stay in flight
      if (kt + 2 < NT) asm volatile("s_waitcnt vmcnt(2)" ::: "memory");
      else             asm volatile("s_waitcnt vmcnt(0)" ::: "memory");
    }
    __builtin_amdgcn_s_barrier();
  }

  // epilogue
  const int cb = col0 + wn * 64 + lm;
  const int rb = row0 + wm * 128 + lk * 4;
#pragma unroll
  for (int i = 0; i < 8; ++i)
#pragma unroll
    for (int j = 0; j < 4; ++j) {
      const int colg = cb + j * 16;
      const float bv = bias ? bias[colg] : 0.0f;
#pragma unroll
      for (int r = 0; r < 4; ++r) {
        const int rowg = rb + i * 16 + r;
        Cbf[(size_t)rowg * N + colg] = f2bf(acc[i][j][r] + bv);
      }
    }
}

// ---------------- split-K bf16 MFMA GEMM (f32 partials) ---------------------
__global__ __launch_bounds__(256)
void gemm_bf16_splitk_kernel(const u16* __restrict__ A, const u16* __restrict__ Bt,
                             float* __restrict__ P, int N, int K, int kLen) {
  __shared__ u16 As[128 * 32];
  __shared__ u16 Bs[128 * 32];
  const int tid = threadIdx.x;
  const int w = tid >> 6, l = tid & 63;
  const int row0 = blockIdx.y * 128, col0 = blockIdx.x * 128;
  const int kbeg = blockIdx.z * kLen, kend = kbeg + kLen;
  float* Pz = P + (size_t)blockIdx.z * S_TOT * N;
  const int wr = (w >> 1) * 64, wc = (w & 1) * 64;
  const int am = l & 15, ak = (l >> 4) * 8;
  const int srow = l >> 2, scol = (l & 3) * 8;

  f32x4 acc[4][4] = {};

  const u16* Abase = A + (size_t)(row0 + srow) * K + scol;
  const u16* Bbase = Bt + (size_t)(col0 + srow) * K + scol;
  const int R0 = (w * 2) * 16, R1 = (w * 2 + 1) * 16;

  for (int k0 = kbeg; k0 < kend; k0 += 32) {
    gld_lds16(Abase + (size_t)R0 * K + k0, &As[R0 * 32]);
    gld_lds16(Abase + (size_t)R1 * K + k0, &As[R1 * 32]);
    gld_lds16(Bbase + (size_t)R0 * K + k0, &Bs[R0 * 32]);
    gld_lds16(Bbase + (size_t)R1 * K + k0, &Bs[R1 * 32]);
    __syncthreads();
    bf16x8 af[4], bfr[4];
#pragma unroll
    for (int i = 0; i < 4; ++i) af[i] = *(const bf16x8*)&As[(wr + i * 16 + am) * 32 + ak];
#pragma unroll
    for (int j = 0; j < 4; ++j) bfr[j] = *(const bf16x8*)&Bs[(wc + j * 16 + am) * 32 + ak];
#pragma unroll
    for (int i = 0; i < 4; ++i)
#pragma unroll
      for (int j = 0; j < 4; ++j)
        acc[i][j] = __builtin_amdgcn_mfma_f32_16x16x32_bf16(af[i], bfr[j], acc[i][j], 0, 0, 0);
    __syncthreads();
  }

  const int rb = wr + (l >> 4) * 4;
  const int cb = wc + (l & 15);
#pragma unroll
  for (int i = 0; i < 4; ++i)
#pragma unroll
    for (int j = 0; j < 4; ++j) {
      const int colg = col0 + cb + j * 16;
#pragma unroll
      for (int r = 0; r < 4; ++r) {
        const int rowg = row0 + rb + i * 16 + r;
        Pz[(size_t)rowg * N + colg] = acc[i][j][r];
      }
    }
}

// ---------------- acc[i] += p1[i] + resid[i]  (O-proj split-K reduce) -------
__global__ __launch_bounds__(256)
void add3_kernel(float* __restrict__ acc, const float* __restrict__ p1,
                 const float* __restrict__ resid) {
  const size_t i = ((size_t)blockIdx.x * 256 + threadIdx.x) * 4;
  float4 a = *(const float4*)(acc + i);
  float4 b = *(const float4*)(p1 + i);
  float4 c = *(const float4*)(resid + i);
  a.x += b.x + c.x; a.y += b.y + c.y; a.z += b.z + c.z; a.w += b.w + c.w;
  *(float4*)(acc + i) = a;
}

// ---------------- down split-K reduce + residual + gated scatter ------------
__global__ __launch_bounds__(256)
void down_finish_kernel(const float* __restrict__ P, const float* __restrict__ x1,
                        const int* __restrict__ tidx, const float* __restrict__ gate,
                        const float* __restrict__ hs, float* __restrict__ out) {
  const int s = blockIdx.x;
  const int b = s >> 10;
  const int t = tidx[s];
  const float gg = gate[s];
  const size_t src = (size_t)s * D_DIM;
  const size_t dst = ((size_t)b * T_LEN + t) * D_DIM;
  const size_t plane = (size_t)S_TOT * D_DIM;
  for (int d = threadIdx.x * 4; d < D_DIM; d += 1024) {
    float4 p0 = *(const float4*)(P + src + d);
    float4 p1 = *(const float4*)(P + plane + src + d);
    float4 xr = *(const float4*)(x1 + src + d);
    float4 hv = *(const float4*)(hs + dst + d);
    float4 r;
    r.x = hv.x + (p0.x + p1.x + xr.x - hv.x) * gg;
    r.y = hv.y + (p0.y + p1.y + xr.y - hv.y) * gg;
    r.z = hv.z + (p0.z + p1.z + xr.z - hv.z) * gg;
    r.w = hv.w + (p0.w + p1.w + xr.w - hv.w) * gg;
    *(float4*)(out + dst + d) = r;
  }
}

// ---------------- RoPE in place on bf16 qkv buffer [S, 6144] ----------------
__global__ __launch_bounds__(256)
void rope_kernel(u16* __restrict__ qkv, const float* __restrict__ cosb,
                 const float* __restrict__ sinb, const int* __restrict__ tidx) {
  const int idx = blockIdx.x * 256 + threadIdx.x;  // < S*H*64
  const int d = idx & 63;
  const int h = (idx >> 6) & 15;
  const int s = idx >> 10;
  const int b = s >> 10;
  const int t = tidx[s];
  const size_t base = (size_t)s * QKV_N + h * 128 + d;
  const size_t cb = ((size_t)b * T_LEN + t) * HD_DIM + d;
  const float c1 = cosb[cb], sn1 = sinb[cb];
  const float c2 = cosb[cb + 64], sn2 = sinb[cb + 64];
  float x1v, x2v;
  x1v = bf2f(qkv[base]); x2v = bf2f(qkv[base + 64]);
  qkv[base] = f2bf(x1v * c1 - x2v * sn1);
  qkv[base + 64] = f2bf(x2v * c2 + x1v * sn2);
  x1v = bf2f(qkv[base + 2048]); x2v = bf2f(qkv[base + 2048 + 64]);
  qkv[base + 2048] = f2bf(x1v * c1 - x2v * sn1);
  qkv[base + 2048 + 64] = f2bf(x2v * c2 + x1v * sn2);
}

// ---------------- MFMA flash attention (8 waves, 2 kv-groups) ---------------
__global__ __launch_bounds__(512, 4)
void attn_mfma_kernel(const u16* __restrict__ QKV, const u16* __restrict__ VT,
                      u16* __restrict__ Og) {
  const int h  = blockIdx.y;
  const int bx = blockIdx.x;
  const int qt = (h < 8) ? (31 - bx) : bx;
  const int q0 = qt * 64;
  const int tid = threadIdx.x;
  const int l  = tid & 63;
  const int w  = tid >> 6;       // 0..7
  const int g  = w >> 2;         // kv group
  const int wq = w & 3;          // q sub-block (16 rows)
  const int lm = l & 15, lk = l >> 4;

  __shared__ __align__(16) unsigned char smem[65536];
  u16* Ks = (u16*)(smem + g * 16384);           // [64 kv][128 d]  swizzled
  u16* Vt = (u16*)(smem + 32768 + g * 16384);   // [128 d][64 kv]  swizzled
  u16* Ps = (u16*)(smem + g * 16384);           // [64 q][64 kv]   aliases Ks

  const u16* Qg  = QKV + h * 128;
  const u16* Kg  = QKV + 2048 + h * 128;
  const u16* Vgt = VT + (size_t)h * 128 * S_TOT;

  bf16x8 qf[4];
  {
    const u16* qrow = Qg + (size_t)(q0 + wq * 16 + lm) * QKV_N;
#pragma unroll
    for (int ks = 0; ks < 4; ++ks) qf[ks] = *(const bf16x8*)&qrow[ks * 32 + lk * 8];
  }

  int ksrc[4], vsrc[4];
#pragma unroll
  for (int p = 0; p < 4; ++p) {
    const int ci = (wq * 4 + p) * 64 + l;
    const int kr = ci >> 4, kc = ci & 15;
    ksrc[p] = kr * QKV_N + ((kc ^ (kr & 7)) * 8);
    const int vr = ci >> 3, vc = ci & 7;
    vsrc[p] = vr * S_TOT + ((vc ^ (vr & 7)) * 8);
  }

  f32x4 oacc[8];
#pragma unroll
  for (int n = 0; n < 8; ++n) oacc[n] = (f32x4){0.f, 0.f, 0.f, 0.f};
  float m_run[4] = {-1e30f, -1e30f, -1e30f, -1e30f};
  float l_run[4] = {0.f, 0.f, 0.f, 0.f};

  const int ntiles = (g == 0) ? (qt / 2 + 1) : ((qt + 1) / 2);
  const int nmax = qt / 2 + 1;
  const float scale = 0.08838834764831845f;

  for (int it = 0; it < nmax; ++it) {
    const int kt = g + 2 * it;
    const int kv0 = kt * 64;
    const bool active = (it < ntiles);
    __syncthreads();
    if (active) {
#pragma unroll
      for (int p = 0; p < 4; ++p) {
        gld_lds16(Kg + (size_t)kv0 * QKV_N + ksrc[p], &Ks[(wq * 4 + p) * 512]);
        gld_lds16(Vgt + kv0 + vsrc[p],               &Vt[(wq * 4 + p) * 512]);
      }
    }
    __syncthreads();

    f32x4 sacc[4];
    if (active) {
#pragma unroll
      for (int j = 0; j < 4; ++j) sacc[j] = (f32x4){0.f, 0.f, 0.f, 0.f};
#pragma unroll
      for (int j = 0; j < 4; ++j) {
        const int row = j * 16 + lm;
#pragma unroll
        for (int ks = 0; ks < 4; ++ks) {
          const int c = ks * 4 + lk;
          const bf16x8 kf = *(const bf16x8*)&(
              (const unsigned char*)Ks)[row * 256 + ((c ^ (row & 7)) << 4)];
          sacc[j] = __builtin_amdgcn_mfma_f32_16x16x32_bf16(qf[ks], kf, sacc[j], 0, 0, 0);
        }
      }
    }
    __syncthreads();

    if (active) {
      float mx[4] = {-1e30f, -1e30f, -1e30f, -1e30f};
#pragma unroll
      for (int j = 0; j < 4; ++j) {
        const int colg = kv0 + j * 16 + lm;
#pragma unroll
        for (int r = 0; r < 4; ++r) {
          const int rowg = q0 + wq * 16 + lk * 4 + r;
          float s = sacc[j][r] * scale;
          s = (colg > rowg) ? -1e30f : s;
          sacc[j][r] = s;
          mx[r] = fmaxf(mx[r], s);
        }
      }
#pragma unroll
      for (int r = 0; r < 4; ++r)
#pragma unroll
        for (int dlt = 1; dlt < 16; dlt <<= 1)
          mx[r] = fmaxf(mx[r], __shfl_xor(mx[r], dlt));
      float alpha[4];
#pragma unroll
      for (int r = 0; r < 4; ++r) {
        const float mnew = fmaxf(m_run[r], mx[r]);
        const float al = __expf(m_run[r] - mnew);
        float sum = 0.f;
#pragma unroll
        for (int j = 0; j < 4; ++j) {
          const float pe = __expf(sacc[j][r] - mnew);
          sacc[j][r] = pe;
          sum += pe;
        }
#pragma unroll
        for (int dlt = 1; dlt < 16; dlt <<= 1) sum += __shfl_xor(sum, dlt);
        l_run[r] = l_run[r] * al + sum;
        m_run[r] = mnew;
        alpha[r] = al;
      }
#pragma unroll
      for (int n = 0; n < 8; ++n)
#pragma unroll
        for (int r = 0; r < 4; ++r) oacc[n][r] *= alpha[r];

#pragma unroll
      for (int j = 0; j < 4; ++j)
#pragma unroll
        for (int r = 0; r < 4; ++r) {
          const int row = wq * 16 + lk * 4 + r;
          *(u16*)&((unsigned char*)Ps)[row * 128 +
              (((j * 16 + lm) * 2) ^ ((row & 7) << 4))] = f2bf(sacc[j][r]);
        }

#pragma unroll
      for (int ks2 = 0; ks2 < 2; ++ks2) {
        const int prow = wq * 16 + lm;
        const bf16x8 pf = *(const bf16x8*)&(
            (const unsigned char*)Ps)[prow * 128 +
                ((ks2 * 64 + lk * 16) ^ ((prow & 7) << 4))];
#pragma unroll
        for (int n = 0; n < 8; ++n) {
          const int vrow = n * 16 + lm;
          const int vc = ks2 * 4 + lk;
          const bf16x8 vf = *(const bf16x8*)&(
              (const unsigned char*)Vt)[vrow * 128 + ((vc ^ (vrow & 7)) << 4)];
          oacc[n] = __builtin_amdgcn_mfma_f32_16x16x32_bf16(pf, vf, oacc[n], 0, 0, 0);
        }
      }
    }
  }

  __syncthreads();
  float* Obuf = (float*)smem;
  float* Mbuf = (float*)(smem + 33792);
  float* Lbuf = (float*)(smem + 34048);
  if (g == 1) {
#pragma unroll
    for (int r = 0; r < 4; ++r) {
      const int row = wq * 16 + lk * 4 + r;
      if (lm == 0) { Mbuf[row] = m_run[r]; Lbuf[row] = l_run[r]; }
#pragma unroll
      for (int n = 0; n < 8; ++n) Obuf[row * 132 + n * 16 + lm] = oacc[n][r];
    }
  }
  __syncthreads();
  if (g == 0) {
    float a0[4], a1[4], linv[4];
#pragma unroll
    for (int r = 0; r < 4; ++r) {
      const int row = wq * 16 + lk * 4 + r;
      const float m1 = Mbuf[row], l1 = Lbuf[row];
      const float M = fmaxf(m_run[r], m1);
      a0[r] = __expf(m_run[r] - M);
      a1[r] = __expf(m1 - M);
      linv[r] = 1.f / (a0[r] * l_run[r] + a1[r] * l1);
    }
#pragma unroll
    for (int n = 0; n < 8; ++n)
#pragma unroll
      for (int r = 0; r < 4; ++r) {
        const int row = wq * 16 + lk * 4 + r;
        const float o = (oacc[n][r] * a0[r] +
                         Obuf[row * 132 + n * 16 + lm] * a1[r]) * linv[r];
        Og[(size_t)(q0 + row) * 2048 + h * 128 + n * 16 + lm] = f2bf(o);
      }
  }
}

// ---------------- silu(gate)*up on fused bf16 gu buffer ---------------------
__global__ __launch_bounds__(256)
void silu_mul_kernel(const u16* __restrict__ gu, u16* __restrict__ out) {
  const size_t i = (size_t)blockIdx.x * 256 + threadIdx.x;  // 4-elem units
  const int s = (int)(i / 1408);
  const int c = (int)(i - (size_t)s * 1408);
  const uint2 g4 = *(const uint2*)&gu[(size_t)s * GU_N + c * 4];
  const uint2 u4 = *(const uint2*)&gu[(size_t)s * GU_N + I_DIM + c * 4];
  float g[4], u[4];
  g[0] = __uint_as_float(g4.x << 16); g[1] = __uint_as_float(g4.x & 0xffff0000u);
  g[2] = __uint_as_float(g4.y << 16); g[3] = __uint_as_float(g4.y & 0xffff0000u);
  u[0] = __uint_as_float(u4.x << 16); u[1] = __uint_as_float(u4.x & 0xffff0000u);
  u[2] = __uint_as_float(u4.y << 16); u[3] = __uint_as_float(u4.y & 0xffff0000u);
  u16 r[4];
#pragma unroll
  for (int j = 0; j < 4; ++j) r[j] = f2bf(g[j] * u[j] / (1.f + __expf(-g[j])));
  u32 a0 = (u32)r[0] | ((u32)r[1] << 16);
  u32 a1 = (u32)r[2] | ((u32)r[3] << 16);
  *(uint2*)&out[(size_t)s * I_DIM + c * 4] = make_uint2(a0, a1);
}

// ---------------------------------------------------------------------------
extern "C" void kernel_launch(void* const* d_in, const int* in_sizes, int n_in,
                              void* d_out, int out_size, void* d_ws, size_t ws_size,
                              hipStream_t stream) {
  (void)in_sizes; (void)n_in; (void)out_size; (void)ws_size;
  const float* hs    = (const float*)d_in[0];
  const float* orig  = (const float*)d_in[1];
  const float* post  = (const float*)d_in[2];
  const float* prior = (const float*)d_in[3];
  const float* cosb  = (const float*)d_in[4];
  const float* sinb  = (const float*)d_in[5];
  const float* q_w = (const float*)d_in[7];
  const float* q_b = (const float*)d_in[8];
  const float* k_w = (const float*)d_in[9];
  const float* k_b = (const float*)d_in[10];
  const float* v_w = (const float*)d_in[11];
  const float* v_b = (const float*)d_in[12];
  const float* o_w = (const float*)d_in[13];
  const float* ln1 = (const float*)d_in[14];
  const float* ln2 = (const float*)d_in[15];
  const float* gate_w = (const float*)d_in[16];
  const float* up_w   = (const float*)d_in[17];
  const float* down_w = (const float*)d_in[18];
  const float* beta_ce = (const float*)d_in[19];
  const float* beta_cu = (const float*)d_in[20];
  const float* ce_off  = (const float*)d_in[21];
  float* out = (float*)d_out;

  char* wsp = (char*)d_ws;
  size_t off = 0;
  auto alloc = [&](size_t n) -> char* {
    char* r = wsp + off; off += (n + 255) & ~(size_t)255; return r;
  };
  const size_t SD4 = (size_t)S_TOT * D_DIM * 4;   // 16 MB

  float* scores  = (float*)alloc((size_t)B_DIM * T_LEN * 4);
  int*   rnk     = (int*)  alloc((size_t)B_DIM * T_LEN * 4);
  int*   tidx    = (int*)  alloc((size_t)S_TOT * 4);
  float* gatebuf = (float*)alloc((size_t)S_TOT * 4);
  float* qkvbias = (float*)alloc((size_t)QKV_N * 4);
  u16* qkvwt = (u16*)alloc((size_t)QKV_N * 2048 * 2);       // 25.2 MB
  u16* owt   = (u16*)alloc((size_t)2048 * 2048 * 2);        //  8.4 MB
  u16* guwt  = (u16*)alloc((size_t)GU_N * 2048 * 2);        // 46.1 MB
  u16* dwt   = (u16*)alloc((size_t)2048 * I_DIM * 2);       // 23.1 MB
  // region A: selh (rms1..O-proj) then h2 (rms2..gate/up)
  char* rA = alloc(SD4);
  float* selh = (float*)rA;
  u16*   h2   = (u16*)rA;
  // region B: h1 (rms1..QKV) then o_attn (attn..O-proj) then mlp_in (silu..down)
  char* rB = alloc((size_t)S_TOT * I_DIM * 2);              // 23.1 MB
  u16* h1     = (u16*)rB;
  u16* o_attn = (u16*)rB;
  u16* mlp_in = (u16*)rB;
  // region C: qkv_bf (QKV..attn) then gu_bf (gate/up..silu) then down-partials
  char* rC = alloc((size_t)S_TOT * GU_N * 2);               // 44 MB
  u16* qkv_bf = (u16*)rC;
  u16* gu_bf  = (u16*)rC;
  float* dpart = (float*)rC;   // 2 x [S,D] f32 partial planes (33.6 MB)
  float* x1  = (float*)alloc(SD4);
  float* x1p = (float*)alloc(SD4);   // contiguous with x1: plane 1
  (void)x1p;
  u16* vT = (u16*)x1;   // pre-transposed V lives in x1 until step 7

  // 0) output starts as a copy of hidden_states; fused qkv bias
  hipMemcpyAsync(out, hs, (size_t)B_DIM * T_LEN * D_DIM * 4,
                 hipMemcpyDeviceToDevice, stream);
  hipMemcpyAsync(qkvbias, q_b, 2048 * 4, hipMemcpyDeviceToDevice, stream);
  hipMemcpyAsync(qkvbias + 2048, k_b, 2048 * 4, hipMemcpyDeviceToDevice, stream);
  hipMemcpyAsync(qkvbias + 4096, v_b, 2048 * 4, hipMemcpyDeviceToDevice, stream);

  // 1) router scores + top-k selection (temporal order)
  router_kernel<<<dim3(B_DIM * T_LEN), 256, 0, stream>>>(orig, post, prior,
                                                         beta_ce, beta_cu, ce_off, scores);
  rank_kernel<<<dim3(8, B_DIM), 256, 0, stream>>>(scores, rnk);
  compact_kernel<<<dim3(B_DIM), 256, 0, stream>>>(scores, rnk, tidx, gatebuf);

  // 2) weight conversions (transpose to [N][K] bf16); fused layouts
  transpose_bf16_kernel<<<dim3(64, 64), 256, 0, stream>>>(q_w, qkvwt, 2048, 2048);
  transpose_bf16_kernel<<<dim3(64, 64), 256, 0, stream>>>(k_w, qkvwt + (size_t)2048 * 2048, 2048, 2048);
  transpose_bf16_kernel<<<dim3(64, 64), 256, 0, stream>>>(v_w, qkvwt + (size_t)4096 * 2048, 2048, 2048);
  transpose_bf16_kernel<<<dim3(64, 64), 256, 0, stream>>>(o_w, owt, 2048, 2048);
  transpose_bf16_kernel<<<dim3(176, 64), 256, 0, stream>>>(gate_w, guwt, 2048, I_DIM);
  transpose_bf16_kernel<<<dim3(176, 64), 256, 0, stream>>>(up_w, guwt + (size_t)I_DIM * 2048, 2048, I_DIM);
  transpose_bf16_kernel<<<dim3(64, 176), 256, 0, stream>>>(down_w, dwt, I_DIM, 2048);

  // 3) gather + rmsnorm1 -> selh (f32), h1 (bf16)
  rmsnorm_kernel<<<dim3(S_TOT), 256, 0, stream>>>(hs, tidx, ln1, selh, h1);

  // 4) fused QKV GEMM (8-phase 256^2) -> qkv_bf (bf16, [S][6144])
  gemm_bf16_8ph_kernel<<<dim3(24, 8), 512, 0, stream>>>(h1, qkvwt, qkv_bf,
                                                        qkvbias, QKV_N, 2048);
  // 5) RoPE in place (q & k halves)
  rope_kernel<<<dim3((S_TOT * H_NUM * 64) / 256), 256, 0, stream>>>(qkv_bf, cosb, sinb, tidx);

  // 5b) pre-transpose V -> vT[h*128+d][s]
  vtrans_kernel<<<dim3(64, 64), 256, 0, stream>>>(qkv_bf, vT);

  // 6) MFMA flash attention -> o_attn (bf16)
  attn_mfma_kernel<<<dim3(32, H_NUM), 512, 0, stream>>>(qkv_bf, vT, o_attn);

  // 7) O-proj split-K=2 -> planes {x1, x1+SD}; reduce (+selh resid) -> x1
  gemm_bf16_splitk_kernel<<<dim3(16, 16, 2), 256, 0, stream>>>(o_attn, owt, x1,
                                                               2048, 2048, 1024);
  add3_kernel<<<dim3((S_TOT * D_DIM) / 1024), 256, 0, stream>>>(
      x1, x1 + (size_t)S_TOT * D_DIM, selh);

  // 8) rmsnorm2 -> h2 (bf16)
  rmsnorm_kernel<<<dim3(S_TOT), 256, 0, stream>>>(x1, nullptr, ln2, nullptr, h2);

  // 9) fused gate/up GEMM (8-phase 256^2) -> gu_bf (bf16, [S][11264])
  gemm_bf16_8ph_kernel<<<dim3(44, 8), 512, 0, stream>>>(h2, guwt, gu_bf,
                                                        nullptr, GU_N, 2048);

  // 10) silu * up -> mlp_in (bf16)
  silu_mul_kernel<<<dim3((S_TOT * (I_DIM / 4)) / 256), 256, 0, stream>>>(gu_bf, mlp_in);

  // 11) down split-K=2 -> planes {rC, rC+SD} (gu_bf dead after silu_mul)
  gemm_bf16_splitk_kernel<<<dim3(16, 16, 2), 256, 0, stream>>>(mlp_in, dwt, dpart,
                                                               2048, 5632, 2816);

  // 12) fused reduce + residual(x1) + gated scatter into out
  down_finish_kernel<<<dim3(S_TOT), 256, 0, stream>>>(dpart, x1, tidx, gatebuf,
                                                      hs, out);
}